// Round 11
// baseline (712.876 us; speedup 1.0000x reference)
//
#include <hip/hip_runtime.h>
#include <hip/hip_bf16.h>
#include <math.h>

#define N_INPUTS 65536
#define NUM_EMB 4096
#define DIM 256
#define TAU_H 9.0e-4f     // half-score threshold (empirically validated r4-r10)
#define CAP 128

typedef __attribute__((ext_vector_type(8))) short bf16x8;
typedef __attribute__((ext_vector_type(4))) float f32x4;

// ---- monotone float<->uint packing ----
__device__ __forceinline__ unsigned enc32(float f) {
    unsigned u = __float_as_uint(f);
    return (u & 0x80000000u) ? ~u : (u | 0x80000000u);
}
__device__ __forceinline__ float dec32(unsigned e) {
    unsigned u = (e & 0x80000000u) ? (e & 0x7FFFFFFFu) : ~e;
    return __uint_as_float(u);
}
__device__ __forceinline__ unsigned short f2bf_rne(float f) {
    unsigned u = __float_as_uint(f);
    return (unsigned short)((u + 0x7FFFu + ((u >> 16) & 1u)) >> 16);
}

// ---- numpy pairwise sum of squares (bit-exact, proven r2) ----
__device__ __forceinline__ float pw128_sq(const float* __restrict__ a) {
    float r[8];
    #pragma unroll
    for (int j = 0; j < 8; ++j) r[j] = __fmul_rn(a[j], a[j]);
    #pragma unroll
    for (int i = 8; i < 128; i += 8)
        #pragma unroll
        for (int j = 0; j < 8; ++j)
            r[j] = __fadd_rn(r[j], __fmul_rn(a[i + j], a[i + j]));
    return __fadd_rn(__fadd_rn(__fadd_rn(r[0], r[1]), __fadd_rn(r[2], r[3])),
                     __fadd_rn(__fadd_rn(r[4], r[5]), __fadd_rn(r[6], r[7])));
}
__device__ __forceinline__ float pw256_sq(const float* __restrict__ a) {
    return __fadd_rn(pw128_sq(a), pw128_sq(a + 128));
}

// ---- prep: stage 64 rows -> row norms (numpy order) + bf16 copy ----
__global__ __launch_bounds__(256) void prep_rows(
        const float* __restrict__ src, float* __restrict__ norms,
        unsigned short* __restrict__ dst_bf) {
    __shared__ float xs[64 * 260];
    const int t = threadIdx.x, b = blockIdx.x;
    const size_t rowbase = (size_t)b * 64;
    const float4* g = (const float4*)(src + rowbase * DIM);
    float4* s4 = (float4*)xs;
    #pragma unroll
    for (int k = 0; k < 16; ++k) {
        int p = t + k * 256, r = p >> 6, c = p & 63;
        s4[r * 65 + c] = g[p];
    }
    __syncthreads();
    if (t < 64) norms[rowbase + t] = pw256_sq(xs + t * 260);
    #pragma unroll
    for (int k = 0; k < 16; ++k) {
        int p = t + k * 256, r = p >> 6, c = p & 63;
        float4 v = s4[r * 65 + c];
        ushort4 u;
        u.x = f2bf_rne(v.x); u.y = f2bf_rne(v.y);
        u.z = f2bf_rne(v.z); u.w = f2bf_rne(v.w);
        ((ushort4*)dst_bf)[(size_t)b * 4096 + p] = u;
    }
}

// ---- exact score, bit-identical to r2 (passed indices exactly) ----
__device__ float exact_score(const float* __restrict__ xr, const float* __restrict__ er,
                             float nx2r, float ne2v) {
    float a = 0.f;
    for (int d = 0; d < DIM; d += 16) {
        float4 xa = *(const float4*)(xr + d);
        float4 xb = *(const float4*)(xr + d + 4);
        float4 xc = *(const float4*)(xr + d + 8);
        float4 xd = *(const float4*)(xr + d + 12);
        float4 e0 = *(const float4*)(er + d);
        float4 e1 = *(const float4*)(er + d + 4);
        float4 e2 = *(const float4*)(er + d + 8);
        float4 e3 = *(const float4*)(er + d + 12);
        a = fmaf(xa.x, e0.x, a); a = fmaf(xa.y, e0.y, a);
        a = fmaf(xa.z, e0.z, a); a = fmaf(xa.w, e0.w, a);
        a = fmaf(xb.x, e1.x, a); a = fmaf(xb.y, e1.y, a);
        a = fmaf(xb.z, e1.z, a); a = fmaf(xb.w, e1.w, a);
        a = fmaf(xc.x, e2.x, a); a = fmaf(xc.y, e2.y, a);
        a = fmaf(xc.z, e2.z, a); a = fmaf(xc.w, e2.w, a);
        a = fmaf(xd.x, e3.x, a); a = fmaf(xd.y, e3.y, a);
        a = fmaf(xd.z, e3.z, a); a = fmaf(xd.w, e3.w, a);
    }
    float t1 = __fadd_rn(nx2r, ne2v);
    return __fsub_rn(t1, __fmul_rn(2.f, a));
}

// ---- pass 1: 64-row x 128-code tiles, 4 waves, 3 blocks/CU ----
// A frags in regs; B double-buffered LDS (swizzled); barrier-free LDS-atomic
// running min; u16 candidates buffered in LDS, flushed once.
__global__ __launch_bounds__(256, 3) void gemm_cand(
        const unsigned short* __restrict__ xbf,
        const unsigned short* __restrict__ cbbf,
        const float* __restrict__ ne2,
        unsigned* __restrict__ cand_cnt,
        unsigned short* __restrict__ cand_ent) {
    __shared__ __align__(16) char Bs[32768];             // 2 x 16KB B dbuf / x-stage union
    __shared__ unsigned short cand_lds[64][CAP];         // 16KB
    __shared__ unsigned rmin_u[64];
    __shared__ unsigned cnt_s[64];

    const int tid = threadIdx.x;
    const int w = tid >> 6, lane = tid & 63;
    const int wr = w >> 1, wc = w & 1;                   // 2x2 wave grid
    const size_t brow = (size_t)blockIdx.x * 64;
    const int srcoff = ((lane & 7) ^ (lane >> 3)) << 4;  // B-staging swizzle

    if (tid < 64) { rmin_u[tid] = 0xFFFFFFFFu; cnt_s[tid] = 0u; }

    // ---- prologue: stage x panel (64 rows x 512B, swizzled) then A frags ----
    #pragma unroll
    for (int i = 0; i < 8; ++i) {
        int chunk = w * 8 + i;                           // 0..31 (1KB = 2 rows)
        int rowg = chunk * 2 + (lane >> 5);
        int src16 = (lane & 31) ^ (rowg & 7);
        const char* ga = (const char*)xbf + (brow + rowg) * 512 + (src16 << 4);
        __builtin_amdgcn_global_load_lds(
            (const __attribute__((address_space(1))) unsigned*)ga,
            (__attribute__((address_space(3))) unsigned*)(Bs + chunk * 1024),
            16, 0, 0);
    }
    __syncthreads();
    bf16x8 af[2][8];
    #pragma unroll
    for (int m = 0; m < 2; ++m) {
        int r = wr * 32 + m * 16 + (lane & 15);
        #pragma unroll
        for (int ks = 0; ks < 8; ++ks) {
            int g = (ks * 4 + (lane >> 4)) ^ (r & 7);
            af[m][ks] = *(const bf16x8*)(Bs + r * 512 + (g << 4));
        }
    }
    __syncthreads();

    auto stageB = [&](int buf, int ct, int tt) {
        #pragma unroll
        for (int i = 0; i < 4; ++i) {
            int chunk = w * 4 + i;                       // 0..15
            int code = ct * 128 + chunk * 8 + (lane >> 3);
            const char* gb = (const char*)cbbf + (size_t)code * 512 + tt * 128 + srcoff;
            __builtin_amdgcn_global_load_lds(
                (const __attribute__((address_space(1))) unsigned*)gb,
                (__attribute__((address_space(3))) unsigned*)(Bs + buf * 16384 + chunk * 1024),
                16, 0, 0);
        }
    };

    f32x4 acc[2][4];
    #pragma unroll
    for (int m = 0; m < 2; ++m)
        #pragma unroll
        for (int n = 0; n < 4; ++n) acc[m][n] = (f32x4){0.f, 0.f, 0.f, 0.f};

    stageB(0, 0, 0);
    __syncthreads();

    for (int ct = 0; ct < 32; ++ct) {
        #pragma unroll
        for (int tt = 0; tt < 4; ++tt) {
            if (!(ct == 31 && tt == 3))
                stageB((tt + 1) & 1, (tt == 3) ? ct + 1 : ct, (tt + 1) & 3);
            const int buf = tt & 1;
            #pragma unroll
            for (int kk = 0; kk < 2; ++kk) {
                bf16x8 bg[4];
                #pragma unroll
                for (int n = 0; n < 4; ++n) {
                    int cc = wc * 64 + n * 16 + (lane & 15);
                    int g = (kk * 4 + (lane >> 4)) ^ (cc & 7);
                    bg[n] = *(const bf16x8*)(Bs + buf * 16384 + cc * 128 + (g << 4));
                }
                #pragma unroll
                for (int m = 0; m < 2; ++m)
                    #pragma unroll
                    for (int n = 0; n < 4; ++n)
                        acc[m][n] = __builtin_amdgcn_mfma_f32_16x16x32_bf16(
                            af[m][tt * 2 + kk], bg[n], acc[m][n], 0, 0, 0);
            }
            __syncthreads();
        }

        // ---- barrier-free epilogue for col tile ct (128 codes) ----
        float ne2h[4];
        #pragma unroll
        for (int n = 0; n < 4; ++n)
            ne2h[n] = 0.5f * ne2[ct * 128 + wc * 64 + n * 16 + (lane & 15)];

        #pragma unroll
        for (int m = 0; m < 2; ++m) {
            #pragma unroll
            for (int j = 0; j < 4; ++j) {
                float v = fminf(fminf(ne2h[0] - acc[m][0][j], ne2h[1] - acc[m][1][j]),
                                fminf(ne2h[2] - acc[m][2][j], ne2h[3] - acc[m][3][j]));
                #pragma unroll
                for (int off = 1; off < 16; off <<= 1)
                    v = fminf(v, __shfl_xor(v, off, 64));
                const int rowl = wr * 32 + m * 16 + (lane >> 4) * 4 + j;
                if ((lane & 15) == 0) atomicMin(&rmin_u[rowl], enc32(v));
                // stale reads of rmin_u only loosen the threshold (superset).
                float th = fminf(dec32(rmin_u[rowl]), v) + TAU_H;
                #pragma unroll
                for (int n = 0; n < 4; ++n) {
                    float s = ne2h[n] - acc[m][n][j];
                    if (s <= th) {
                        int col = ct * 128 + wc * 64 + n * 16 + (lane & 15);
                        unsigned pos = atomicAdd(&cnt_s[rowl], 1u);
                        if (pos < CAP) cand_lds[rowl][pos] = (unsigned short)col;
                    }
                }
                acc[m][0][j] = 0.f; acc[m][1][j] = 0.f;
                acc[m][2][j] = 0.f; acc[m][3][j] = 0.f;
            }
        }
    }

    // ---- single coalesced flush (uint4) ----
    __syncthreads();
    {
        uint4* dst = (uint4*)(cand_ent + brow * CAP);
        const uint4* srcl = (const uint4*)&cand_lds[0][0];
        #pragma unroll
        for (int k = 0; k < 4; ++k)
            dst[tid + k * 256] = srcl[tid + k * 256];
    }
    if (tid < 64) cand_cnt[brow + tid] = cnt_s[tid];
}

// ---- pass 2: exact refine (one wave per row) ----
__global__ __launch_bounds__(256) void refine_kernel(
        const float* __restrict__ x, const float* __restrict__ cb,
        const float* __restrict__ ne2, const float* __restrict__ nx2,
        const unsigned* __restrict__ cand_cnt,
        const unsigned short* __restrict__ cand_ent,
        float* __restrict__ out_idx, int* __restrict__ counts) {
    const size_t row = (size_t)blockIdx.x * 4 + (threadIdx.x >> 6);
    const int lane = threadIdx.x & 63;
    const unsigned cnt = cand_cnt[row];
    const float nx2r = nx2[row];
    const float* xr = x + row * DIM;
    unsigned long long best = ~0ull;

    if (cnt <= CAP) {
        for (unsigned p = lane; p < cnt; p += 64) {
            int code = cand_ent[row * CAP + p];
            float s = exact_score(xr, cb + (size_t)code * DIM, nx2r, ne2[code]);
            unsigned long long pk = ((unsigned long long)enc32(s) << 32) | (unsigned)code;
            best = best < pk ? best : pk;
        }
    }
    #pragma unroll
    for (int off = 1; off < 64; off <<= 1) {
        unsigned long long o = __shfl_xor(best, off, 64);
        best = best < o ? best : o;
    }
    if (best == ~0ull) {   // overflow / empty: exact full scan (always correct)
        unsigned long long b2 = ~0ull;
        for (int c = lane; c < NUM_EMB; c += 64) {
            float s = exact_score(xr, cb + (size_t)c * DIM, nx2r, ne2[c]);
            unsigned long long pk = ((unsigned long long)enc32(s) << 32) | (unsigned)c;
            b2 = b2 < pk ? b2 : pk;
        }
        #pragma unroll
        for (int off = 1; off < 64; off <<= 1) {
            unsigned long long o = __shfl_xor(b2, off, 64);
            b2 = b2 < o ? b2 : o;
        }
        best = b2;
    }
    if (lane == 0) {
        int idx = (int)(best & 0xFFFFFFFFull);
        idx = max(0, min(NUM_EMB - 1, idx));
        out_idx[row] = (float)idx;
        atomicAdd(&counts[idx], 1);
    }
}

// ---- pass 3: gather quantized + loss partials ----
__global__ __launch_bounds__(256) void outputs_kernel(
        const float* __restrict__ x, const float* __restrict__ cb,
        const float* __restrict__ out_idx, float* __restrict__ out_q,
        float* __restrict__ partials) {
    __shared__ float red[256];
    const int t = threadIdx.x, b = blockIdx.x;
    const size_t rowbase = (size_t)b * 64;
    const int r = t >> 2, c0 = (t & 3) * 16;
    const size_t row = rowbase + r;
    int qi = (int)out_idx[row];
    qi = max(0, min(NUM_EMB - 1, qi));
    const float4* crq = (const float4*)(cb + (size_t)qi * DIM);
    const float4* xr4 = (const float4*)(x + row * DIM);
    float4* oq = (float4*)(out_q + row * DIM);
    float ss = 0.f;
    #pragma unroll
    for (int k = 0; k < 16; ++k) {
        float4 q = crq[c0 + k];
        float4 xv = xr4[c0 + k];
        oq[c0 + k] = q;
        float dx = xv.x - q.x, dy = xv.y - q.y, dz = xv.z - q.z, dw = xv.w - q.w;
        ss += dx * dx + dy * dy + dz * dz + dw * dw;
    }
    red[t] = ss; __syncthreads();
    for (int st = 128; st; st >>= 1) {
        if (t < st) red[t] += red[t + st];
        __syncthreads();
    }
    if (t == 0) partials[b] = red[0];
}

__global__ void finalize_kernel(const float* __restrict__ partials, int np,
                                const int* __restrict__ counts,
                                float* __restrict__ out_loss,
                                float* __restrict__ out_perp) {
    __shared__ double sh[256];
    const int t = threadIdx.x;
    double s = 0.0;
    for (int i = t; i < np; i += 256) s += (double)partials[i];
    sh[t] = s; __syncthreads();
    for (int st = 128; st; st >>= 1) { if (t < st) sh[t] += sh[t + st]; __syncthreads(); }
    double sse = sh[0];
    __syncthreads();
    double h = 0.0;
    for (int k = t; k < NUM_EMB; k += 256) {
        double p = (double)counts[k] / (double)N_INPUTS;
        h -= p * log(p + 1e-10);
    }
    sh[t] = h; __syncthreads();
    for (int st = 128; st; st >>= 1) { if (t < st) sh[t] += sh[t + st]; __syncthreads(); }
    if (t == 0) {
        double mse = sse / ((double)N_INPUTS * (double)DIM);
        out_loss[0] = (float)(1.25 * mse);
        out_perp[0] = (float)exp(sh[0]);
    }
}

extern "C" void kernel_launch(void* const* d_in, const int* in_sizes, int n_in,
                              void* d_out, int out_size, void* d_ws, size_t ws_size,
                              hipStream_t stream) {
    const float* x  = (const float*)d_in[0];
    const float* cb = (const float*)d_in[1];
    float* out      = (float*)d_out;

    float* out_q    = out;                           // 16777216 f32 (64 MiB)
    float* out_loss = out + (size_t)N_INPUTS * DIM;
    float* out_perp = out_loss + 1;
    float* out_idx  = out_perp + 1;

    // scratch inside out_q region (rewritten by outputs_kernel at the end)
    char* sc = (char*)out_q;
    unsigned short* cbbf     = (unsigned short*)(sc);               // 2 MB @0
    unsigned short* xbf      = (unsigned short*)(sc + 2097152);     // 32 MB @2MB
    unsigned short* cand_ent = (unsigned short*)(sc + 35651584);    // 16 MB @34MB
    unsigned* cand_cnt       = (unsigned*)(sc + 52428800);          // 256 KB @50MB

    float* ne2      = (float*)d_ws;                       // 16 KB
    int*   counts   = (int*)((char*)d_ws + 16384);        // 16 KB
    float* partials = (float*)((char*)d_ws + 32768);      // 4 KB
    float* nx2      = (float*)((char*)d_ws + 36864);      // 256 KB

    hipMemsetAsync(counts, 0, NUM_EMB * sizeof(int), stream);

    prep_rows<<<NUM_EMB / 64, 256, 0, stream>>>(cb, ne2, cbbf);
    prep_rows<<<N_INPUTS / 64, 256, 0, stream>>>(x, nx2, xbf);

    gemm_cand<<<N_INPUTS / 64, 256, 0, stream>>>(xbf, cbbf, ne2, cand_cnt, cand_ent);
    refine_kernel<<<N_INPUTS / 4, 256, 0, stream>>>(x, cb, ne2, nx2, cand_cnt, cand_ent,
                                                    out_idx, counts);
    outputs_kernel<<<N_INPUTS / 64, 256, 0, stream>>>(x, cb, out_idx, out_q, partials);
    finalize_kernel<<<1, 256, 0, stream>>>(partials, N_INPUTS / 64, counts,
                                           out_loss, out_perp);
}

// Round 12
// 705.629 us; speedup vs baseline: 1.0103x; 1.0103x over previous
//
#include <hip/hip_runtime.h>
#include <hip/hip_bf16.h>
#include <math.h>

#define N_INPUTS 65536
#define NUM_EMB 4096
#define DIM 256
#define TAU_H 9.0e-4f     // half-score threshold (empirically validated r4-r11)
#define CAP 96
#define EPS_T 1.0e-4f     // tree-vs-serial dot guard in refine

typedef __attribute__((ext_vector_type(8))) short bf16x8;
typedef __attribute__((ext_vector_type(4))) float f32x4;

// ---- monotone float<->uint packing ----
__device__ __forceinline__ unsigned enc32(float f) {
    unsigned u = __float_as_uint(f);
    return (u & 0x80000000u) ? ~u : (u | 0x80000000u);
}
__device__ __forceinline__ float dec32(unsigned e) {
    unsigned u = (e & 0x80000000u) ? (e & 0x7FFFFFFFu) : ~e;
    return __uint_as_float(u);
}
__device__ __forceinline__ unsigned short f2bf_rne(float f) {
    unsigned u = __float_as_uint(f);
    return (unsigned short)((u + 0x7FFFu + ((u >> 16) & 1u)) >> 16);
}

// ---- numpy pairwise sum of squares (bit-exact, proven r2) ----
__device__ __forceinline__ float pw128_sq(const float* __restrict__ a) {
    float r[8];
    #pragma unroll
    for (int j = 0; j < 8; ++j) r[j] = __fmul_rn(a[j], a[j]);
    #pragma unroll
    for (int i = 8; i < 128; i += 8)
        #pragma unroll
        for (int j = 0; j < 8; ++j)
            r[j] = __fadd_rn(r[j], __fmul_rn(a[i + j], a[i + j]));
    return __fadd_rn(__fadd_rn(__fadd_rn(r[0], r[1]), __fadd_rn(r[2], r[3])),
                     __fadd_rn(__fadd_rn(r[4], r[5]), __fadd_rn(r[6], r[7])));
}
__device__ __forceinline__ float pw256_sq(const float* __restrict__ a) {
    return __fadd_rn(pw128_sq(a), pw128_sq(a + 128));
}

// ---- prep: stage 64 rows -> row norms (numpy order) + bf16 copy ----
__global__ __launch_bounds__(256) void prep_rows(
        const float* __restrict__ src, float* __restrict__ norms,
        unsigned short* __restrict__ dst_bf) {
    __shared__ float xs[64 * 260];
    const int t = threadIdx.x, b = blockIdx.x;
    const size_t rowbase = (size_t)b * 64;
    const float4* g = (const float4*)(src + rowbase * DIM);
    float4* s4 = (float4*)xs;
    #pragma unroll
    for (int k = 0; k < 16; ++k) {
        int p = t + k * 256, r = p >> 6, c = p & 63;
        s4[r * 65 + c] = g[p];
    }
    __syncthreads();
    if (t < 64) norms[rowbase + t] = pw256_sq(xs + t * 260);
    #pragma unroll
    for (int k = 0; k < 16; ++k) {
        int p = t + k * 256, r = p >> 6, c = p & 63;
        float4 v = s4[r * 65 + c];
        ushort4 u;
        u.x = f2bf_rne(v.x); u.y = f2bf_rne(v.y);
        u.z = f2bf_rne(v.z); u.w = f2bf_rne(v.w);
        ((ushort4*)dst_bf)[(size_t)b * 4096 + p] = u;
    }
}

// ---- exact score, bit-identical to r2 (final-decision arithmetic) ----
__device__ float exact_score(const float* __restrict__ xr, const float* __restrict__ er,
                             float nx2r, float ne2v) {
    float a = 0.f;
    for (int d = 0; d < DIM; d += 16) {
        float4 xa = *(const float4*)(xr + d);
        float4 xb = *(const float4*)(xr + d + 4);
        float4 xc = *(const float4*)(xr + d + 8);
        float4 xd = *(const float4*)(xr + d + 12);
        float4 e0 = *(const float4*)(er + d);
        float4 e1 = *(const float4*)(er + d + 4);
        float4 e2 = *(const float4*)(er + d + 8);
        float4 e3 = *(const float4*)(er + d + 12);
        a = fmaf(xa.x, e0.x, a); a = fmaf(xa.y, e0.y, a);
        a = fmaf(xa.z, e0.z, a); a = fmaf(xa.w, e0.w, a);
        a = fmaf(xb.x, e1.x, a); a = fmaf(xb.y, e1.y, a);
        a = fmaf(xb.z, e1.z, a); a = fmaf(xb.w, e1.w, a);
        a = fmaf(xc.x, e2.x, a); a = fmaf(xc.y, e2.y, a);
        a = fmaf(xc.z, e2.z, a); a = fmaf(xc.w, e2.w, a);
        a = fmaf(xd.x, e3.x, a); a = fmaf(xd.y, e3.y, a);
        a = fmaf(xd.z, e3.z, a); a = fmaf(xd.w, e3.w, a);
    }
    float t1 = __fadd_rn(nx2r, ne2v);
    return __fsub_rn(t1, __fmul_rn(2.f, a));
}

// ---- 16-element slice dot (used 16-lane-cooperatively in refine) ----
__device__ __forceinline__ float slice_dot16(const float4* xv, const float* __restrict__ er) {
    float4 e0 = *(const float4*)(er);
    float4 e1 = *(const float4*)(er + 4);
    float4 e2 = *(const float4*)(er + 8);
    float4 e3 = *(const float4*)(er + 12);
    float a = 0.f;
    a = fmaf(xv[0].x, e0.x, a); a = fmaf(xv[0].y, e0.y, a);
    a = fmaf(xv[0].z, e0.z, a); a = fmaf(xv[0].w, e0.w, a);
    a = fmaf(xv[1].x, e1.x, a); a = fmaf(xv[1].y, e1.y, a);
    a = fmaf(xv[1].z, e1.z, a); a = fmaf(xv[1].w, e1.w, a);
    a = fmaf(xv[2].x, e2.x, a); a = fmaf(xv[2].y, e2.y, a);
    a = fmaf(xv[2].z, e2.z, a); a = fmaf(xv[2].w, e2.w, a);
    a = fmaf(xv[3].x, e3.x, a); a = fmaf(xv[3].y, e3.y, a);
    a = fmaf(xv[3].z, e3.z, a); a = fmaf(xv[3].w, e3.w, a);
    return a;
}

// ---- pass 1: 64-row x 128-code tiles, counted-vmcnt 4-buffer pipeline ----
__global__ __launch_bounds__(256, 2) void gemm_cand(
        const unsigned short* __restrict__ xbf,
        const unsigned short* __restrict__ cbbf,
        const float* __restrict__ ne2,
        unsigned* __restrict__ cand_cnt,
        unsigned short* __restrict__ cand_ent) {
    __shared__ __align__(16) char Bs[65536];             // 4 x 16KB B rotation / x-stage union
    __shared__ unsigned short cand_lds[64][CAP];         // 12KB
    __shared__ unsigned rmin_u[64];
    __shared__ unsigned cnt_s[64];

    const int tid = threadIdx.x;
    const int w = tid >> 6, lane = tid & 63;
    const int wr = w >> 1, wc = w & 1;                   // 2x2 wave grid
    const size_t brow = (size_t)blockIdx.x * 64;
    const int srcoff = ((lane & 7) ^ (lane >> 3)) << 4;  // B-staging swizzle

    if (tid < 64) { rmin_u[tid] = 0xFFFFFFFFu; cnt_s[tid] = 0u; }

    // ---- prologue: stage x panel (64 rows x 512B, swizzled) then A frags ----
    #pragma unroll
    for (int i = 0; i < 8; ++i) {
        int chunk = w * 8 + i;                           // 0..31 (1KB = 2 rows)
        int rowg = chunk * 2 + (lane >> 5);
        int src16 = (lane & 31) ^ (rowg & 7);
        const char* ga = (const char*)xbf + (brow + rowg) * 512 + (src16 << 4);
        __builtin_amdgcn_global_load_lds(
            (const __attribute__((address_space(1))) unsigned*)ga,
            (__attribute__((address_space(3))) unsigned*)(Bs + chunk * 1024),
            16, 0, 0);
    }
    __syncthreads();
    bf16x8 af[2][8];
    #pragma unroll
    for (int m = 0; m < 2; ++m) {
        int r = wr * 32 + m * 16 + (lane & 15);
        #pragma unroll
        for (int ks = 0; ks < 8; ++ks) {
            int g = (ks * 4 + (lane >> 4)) ^ (r & 7);
            af[m][ks] = *(const bf16x8*)(Bs + r * 512 + (g << 4));
        }
    }
    __syncthreads();

    auto stageB = [&](int buf, int ct, int tt) {
        #pragma unroll
        for (int i = 0; i < 4; ++i) {
            int chunk = w * 4 + i;                       // 0..15
            int code = ct * 128 + chunk * 8 + (lane >> 3);
            const char* gb = (const char*)cbbf + (size_t)code * 512 + tt * 128 + srcoff;
            __builtin_amdgcn_global_load_lds(
                (const __attribute__((address_space(1))) unsigned*)gb,
                (__attribute__((address_space(3))) unsigned*)(Bs + buf * 16384 + chunk * 1024),
                16, 0, 0);
        }
    };

    f32x4 acc[2][4];
    #pragma unroll
    for (int m = 0; m < 2; ++m)
        #pragma unroll
        for (int n = 0; n < 4; ++n) acc[m][n] = (f32x4){0.f, 0.f, 0.f, 0.f};

    // steps s = ct*4 + tt, 128 total; buffer s&3; staged at step s-2.
    stageB(0, 0, 0);
    stageB(1, 0, 1);

    #pragma unroll 4
    for (int s = 0; s < 128; ++s) {
        const int tt = s & 3;
        if (s < 126) {
            const int s2 = s + 2;
            stageB(s2 & 3, s2 >> 2, s2 & 3);
        }
        // counted waits: loads for buffer s&3 are always older than the 8 newest
        if (s < 126)       asm volatile("s_waitcnt vmcnt(8)" ::: "memory");
        else if (s == 126) asm volatile("s_waitcnt vmcnt(4)" ::: "memory");
        else               asm volatile("s_waitcnt vmcnt(0)" ::: "memory");
        __builtin_amdgcn_s_barrier();
        __builtin_amdgcn_sched_barrier(0);

        const int buf = s & 3;
        #pragma unroll
        for (int kk = 0; kk < 2; ++kk) {
            bf16x8 bg[4];
            #pragma unroll
            for (int n = 0; n < 4; ++n) {
                int cc = wc * 64 + n * 16 + (lane & 15);
                int g = (kk * 4 + (lane >> 4)) ^ (cc & 7);
                bg[n] = *(const bf16x8*)(Bs + buf * 16384 + cc * 128 + (g << 4));
            }
            #pragma unroll
            for (int m = 0; m < 2; ++m)
                #pragma unroll
                for (int n = 0; n < 4; ++n)
                    acc[m][n] = __builtin_amdgcn_mfma_f32_16x16x32_bf16(
                        af[m][tt * 2 + kk], bg[n], acc[m][n], 0, 0, 0);
        }

        if (tt == 3) {
            // ---- barrier-free epilogue for col tile ct (128 codes) ----
            const int ct = s >> 2;
            float ne2h[4];
            #pragma unroll
            for (int n = 0; n < 4; ++n)
                ne2h[n] = 0.5f * ne2[ct * 128 + wc * 64 + n * 16 + (lane & 15)];

            #pragma unroll
            for (int m = 0; m < 2; ++m) {
                #pragma unroll
                for (int j = 0; j < 4; ++j) {
                    float v = fminf(fminf(ne2h[0] - acc[m][0][j], ne2h[1] - acc[m][1][j]),
                                    fminf(ne2h[2] - acc[m][2][j], ne2h[3] - acc[m][3][j]));
                    #pragma unroll
                    for (int off = 1; off < 16; off <<= 1)
                        v = fminf(v, __shfl_xor(v, off, 64));
                    const int rowl = wr * 32 + m * 16 + (lane >> 4) * 4 + j;
                    if ((lane & 15) == 0) atomicMin(&rmin_u[rowl], enc32(v));
                    // stale reads of rmin_u only loosen the threshold (superset).
                    float th = fminf(dec32(rmin_u[rowl]), v) + TAU_H;
                    #pragma unroll
                    for (int n = 0; n < 4; ++n) {
                        float sc = ne2h[n] - acc[m][n][j];
                        if (sc <= th) {
                            int col = ct * 128 + wc * 64 + n * 16 + (lane & 15);
                            unsigned pos = atomicAdd(&cnt_s[rowl], 1u);
                            if (pos < CAP) cand_lds[rowl][pos] = (unsigned short)col;
                        }
                    }
                    acc[m][0][j] = 0.f; acc[m][1][j] = 0.f;
                    acc[m][2][j] = 0.f; acc[m][3][j] = 0.f;
                }
            }
        }
    }

    // ---- single coalesced flush ----
    __syncthreads();
    {
        uint4* dst = (uint4*)(cand_ent + brow * CAP);    // 64*96*2B = 12288B = 768 uint4
        const uint4* srcl = (const uint4*)&cand_lds[0][0];
        #pragma unroll
        for (int k = 0; k < 3; ++k)
            dst[tid + k * 256] = srcl[tid + k * 256];
    }
    if (tid < 64) cand_cnt[brow + tid] = cnt_s[tid];
}

// ---- pass 2: refine — 16-lane-parallel tree scoring, serial-exact survivors ----
__global__ __launch_bounds__(256) void refine_kernel(
        const float* __restrict__ x, const float* __restrict__ cb,
        const float* __restrict__ ne2, const float* __restrict__ nx2,
        const unsigned* __restrict__ cand_cnt,
        const unsigned short* __restrict__ cand_ent,
        float* __restrict__ out_idx, int* __restrict__ counts) {
    __shared__ float tsc[4][CAP];
    const int wid = threadIdx.x >> 6;
    const size_t row = (size_t)blockIdx.x * 4 + wid;
    const int lane = threadIdx.x & 63;
    const int g = lane >> 4, e = lane & 15;
    const unsigned cnt = cand_cnt[row];
    const float nx2r = nx2[row];
    const float* xr = x + row * DIM;
    float4 xv[4];
    {
        const float4* xp = (const float4*)(xr + e * 16);
        xv[0] = xp[0]; xv[1] = xp[1]; xv[2] = xp[2]; xv[3] = xp[3];
    }
    unsigned long long best = ~0ull;

    if (cnt <= CAP) {
        float mt = INFINITY;
        for (unsigned base = 0; base < cnt; base += 4) {
            unsigned p = base + g;
            bool valid = p < cnt;
            int code = valid ? (int)cand_ent[row * CAP + p] : 0;
            float d = slice_dot16(xv, cb + (size_t)code * DIM + e * 16);
            d += __shfl_xor(d, 1); d += __shfl_xor(d, 2);
            d += __shfl_xor(d, 4); d += __shfl_xor(d, 8);
            float s = __fsub_rn(__fadd_rn(nx2r, ne2[code]), __fmul_rn(2.f, d));
            if (valid) {
                if (e == 0) tsc[wid][p] = s;
                mt = fminf(mt, s);
            }
        }
        mt = fminf(mt, __shfl_xor(mt, 16));
        mt = fminf(mt, __shfl_xor(mt, 32));
        const float thr = mt + EPS_T;
        for (unsigned p = lane; p < cnt; p += 64) {
            if (tsc[wid][p] <= thr) {
                int code = cand_ent[row * CAP + p];
                float s = exact_score(xr, cb + (size_t)code * DIM, nx2r, ne2[code]);
                unsigned long long pk = ((unsigned long long)enc32(s) << 32) | (unsigned)code;
                best = best < pk ? best : pk;
            }
        }
        #pragma unroll
        for (int off = 1; off < 64; off <<= 1) {
            unsigned long long o = __shfl_xor(best, off, 64);
            best = best < o ? best : o;
        }
    }
    if (best == ~0ull) {   // overflow / empty: full scan (tree prefilter + exact)
        float mt = INFINITY;
        for (int base = 0; base < NUM_EMB; base += 4) {
            int code = base + g;
            float d = slice_dot16(xv, cb + (size_t)code * DIM + e * 16);
            d += __shfl_xor(d, 1); d += __shfl_xor(d, 2);
            d += __shfl_xor(d, 4); d += __shfl_xor(d, 8);
            float s = __fsub_rn(__fadd_rn(nx2r, ne2[code]), __fmul_rn(2.f, d));
            mt = fminf(mt, s);
        }
        mt = fminf(mt, __shfl_xor(mt, 16));
        mt = fminf(mt, __shfl_xor(mt, 32));
        const float thr = mt + EPS_T;
        unsigned long long b2 = ~0ull;
        for (int base = 0; base < NUM_EMB; base += 4) {
            int code = base + g;
            float d = slice_dot16(xv, cb + (size_t)code * DIM + e * 16);
            d += __shfl_xor(d, 1); d += __shfl_xor(d, 2);
            d += __shfl_xor(d, 4); d += __shfl_xor(d, 8);
            float s = __fsub_rn(__fadd_rn(nx2r, ne2[code]), __fmul_rn(2.f, d));
            if (s <= thr && e == 0) {
                float se = exact_score(xr, cb + (size_t)code * DIM, nx2r, ne2[code]);
                unsigned long long pk = ((unsigned long long)enc32(se) << 32) | (unsigned)code;
                b2 = b2 < pk ? b2 : pk;
            }
        }
        #pragma unroll
        for (int off = 1; off < 64; off <<= 1) {
            unsigned long long o = __shfl_xor(b2, off, 64);
            b2 = b2 < o ? b2 : o;
        }
        best = b2;
    }
    if (lane == 0) {
        int idx = (int)(best & 0xFFFFFFFFull);
        idx = max(0, min(NUM_EMB - 1, idx));
        out_idx[row] = (float)idx;
        atomicAdd(&counts[idx], 1);
    }
}

// ---- pass 3: gather quantized + loss partials ----
__global__ __launch_bounds__(256) void outputs_kernel(
        const float* __restrict__ x, const float* __restrict__ cb,
        const float* __restrict__ out_idx, float* __restrict__ out_q,
        float* __restrict__ partials) {
    __shared__ float red[256];
    const int t = threadIdx.x, b = blockIdx.x;
    const size_t rowbase = (size_t)b * 64;
    const int r = t >> 2, c0 = (t & 3) * 16;
    const size_t row = rowbase + r;
    int qi = (int)out_idx[row];
    qi = max(0, min(NUM_EMB - 1, qi));
    const float4* crq = (const float4*)(cb + (size_t)qi * DIM);
    const float4* xr4 = (const float4*)(x + row * DIM);
    float4* oq = (float4*)(out_q + row * DIM);
    float ss = 0.f;
    #pragma unroll
    for (int k = 0; k < 16; ++k) {
        float4 q = crq[c0 + k];
        float4 xv = xr4[c0 + k];
        oq[c0 + k] = q;
        float dx = xv.x - q.x, dy = xv.y - q.y, dz = xv.z - q.z, dw = xv.w - q.w;
        ss += dx * dx + dy * dy + dz * dz + dw * dw;
    }
    red[t] = ss; __syncthreads();
    for (int st = 128; st; st >>= 1) {
        if (t < st) red[t] += red[t + st];
        __syncthreads();
    }
    if (t == 0) partials[b] = red[0];
}

__global__ void finalize_kernel(const float* __restrict__ partials, int np,
                                const int* __restrict__ counts,
                                float* __restrict__ out_loss,
                                float* __restrict__ out_perp) {
    __shared__ double sh[256];
    const int t = threadIdx.x;
    double s = 0.0;
    for (int i = t; i < np; i += 256) s += (double)partials[i];
    sh[t] = s; __syncthreads();
    for (int st = 128; st; st >>= 1) { if (t < st) sh[t] += sh[t + st]; __syncthreads(); }
    double sse = sh[0];
    __syncthreads();
    double h = 0.0;
    for (int k = t; k < NUM_EMB; k += 256) {
        double p = (double)counts[k] / (double)N_INPUTS;
        h -= p * log(p + 1e-10);
    }
    sh[t] = h; __syncthreads();
    for (int st = 128; st; st >>= 1) { if (t < st) sh[t] += sh[t + st]; __syncthreads(); }
    if (t == 0) {
        double mse = sse / ((double)N_INPUTS * (double)DIM);
        out_loss[0] = (float)(1.25 * mse);
        out_perp[0] = (float)exp(sh[0]);
    }
}

extern "C" void kernel_launch(void* const* d_in, const int* in_sizes, int n_in,
                              void* d_out, int out_size, void* d_ws, size_t ws_size,
                              hipStream_t stream) {
    const float* x  = (const float*)d_in[0];
    const float* cb = (const float*)d_in[1];
    float* out      = (float*)d_out;

    float* out_q    = out;                           // 16777216 f32 (64 MiB)
    float* out_loss = out + (size_t)N_INPUTS * DIM;
    float* out_perp = out_loss + 1;
    float* out_idx  = out_perp + 1;

    // scratch inside out_q region (rewritten by outputs_kernel at the end)
    char* sc = (char*)out_q;
    unsigned short* cbbf     = (unsigned short*)(sc);               // 2 MB @0
    unsigned short* xbf      = (unsigned short*)(sc + 2097152);     // 32 MB @2MB
    unsigned short* cand_ent = (unsigned short*)(sc + 35651584);    // 12.6 MB @34MB
    unsigned* cand_cnt       = (unsigned*)(sc + 52428800);          // 256 KB @50MB

    float* ne2      = (float*)d_ws;                       // 16 KB
    int*   counts   = (int*)((char*)d_ws + 16384);        // 16 KB
    float* partials = (float*)((char*)d_ws + 32768);      // 4 KB
    float* nx2      = (float*)((char*)d_ws + 36864);      // 256 KB

    hipMemsetAsync(counts, 0, NUM_EMB * sizeof(int), stream);

    prep_rows<<<NUM_EMB / 64, 256, 0, stream>>>(cb, ne2, cbbf);
    prep_rows<<<N_INPUTS / 64, 256, 0, stream>>>(x, nx2, xbf);

    gemm_cand<<<N_INPUTS / 64, 256, 0, stream>>>(xbf, cbbf, ne2, cand_cnt, cand_ent);
    refine_kernel<<<N_INPUTS / 4, 256, 0, stream>>>(x, cb, ne2, nx2, cand_cnt, cand_ent,
                                                    out_idx, counts);
    outputs_kernel<<<N_INPUTS / 64, 256, 0, stream>>>(x, cb, out_idx, out_q, partials);
    finalize_kernel<<<1, 256, 0, stream>>>(partials, N_INPUTS / 64, counts,
                                           out_loss, out_perp);
}

// Round 13
// 649.875 us; speedup vs baseline: 1.0969x; 1.0858x over previous
//
#include <hip/hip_runtime.h>
#include <hip/hip_bf16.h>
#include <math.h>

#define N_INPUTS 65536
#define NUM_EMB 4096
#define DIM 256
#define TAU_H 9.0e-4f     // half-score threshold (empirically validated r4-r12)
#define CAP 96
#define QSC 1.0e6f
#define EPS_T 1.0e-4f     // tree-vs-serial dot guard (fallback only)

typedef __attribute__((ext_vector_type(8))) short bf16x8;
typedef __attribute__((ext_vector_type(4))) float f32x4;

// ---- monotone float<->uint packing ----
__device__ __forceinline__ unsigned enc32(float f) {
    unsigned u = __float_as_uint(f);
    return (u & 0x80000000u) ? ~u : (u | 0x80000000u);
}
__device__ __forceinline__ float dec32(unsigned e) {
    unsigned u = (e & 0x80000000u) ? (e & 0x7FFFFFFFu) : ~e;
    return __uint_as_float(u);
}
__device__ __forceinline__ unsigned short f2bf_rne(float f) {
    unsigned u = __float_as_uint(f);
    return (unsigned short)((u + 0x7FFFu + ((u >> 16) & 1u)) >> 16);
}

// ---- numpy pairwise sum of squares (bit-exact, proven r2) ----
__device__ __forceinline__ float pw128_sq(const float* __restrict__ a) {
    float r[8];
    #pragma unroll
    for (int j = 0; j < 8; ++j) r[j] = __fmul_rn(a[j], a[j]);
    #pragma unroll
    for (int i = 8; i < 128; i += 8)
        #pragma unroll
        for (int j = 0; j < 8; ++j)
            r[j] = __fadd_rn(r[j], __fmul_rn(a[i + j], a[i + j]));
    return __fadd_rn(__fadd_rn(__fadd_rn(r[0], r[1]), __fadd_rn(r[2], r[3])),
                     __fadd_rn(__fadd_rn(r[4], r[5]), __fadd_rn(r[6], r[7])));
}
__device__ __forceinline__ float pw256_sq(const float* __restrict__ a) {
    return __fadd_rn(pw128_sq(a), pw128_sq(a + 128));
}

// ---- prep: stage 64 rows -> row norms (numpy order) + bf16 copy ----
__global__ __launch_bounds__(256) void prep_rows(
        const float* __restrict__ src, float* __restrict__ norms,
        unsigned short* __restrict__ dst_bf) {
    __shared__ float xs[64 * 260];
    const int t = threadIdx.x, b = blockIdx.x;
    const size_t rowbase = (size_t)b * 64;
    const float4* g = (const float4*)(src + rowbase * DIM);
    float4* s4 = (float4*)xs;
    #pragma unroll
    for (int k = 0; k < 16; ++k) {
        int p = t + k * 256, r = p >> 6, c = p & 63;
        s4[r * 65 + c] = g[p];
    }
    __syncthreads();
    if (t < 64) norms[rowbase + t] = pw256_sq(xs + t * 260);
    #pragma unroll
    for (int k = 0; k < 16; ++k) {
        int p = t + k * 256, r = p >> 6, c = p & 63;
        float4 v = s4[r * 65 + c];
        ushort4 u;
        u.x = f2bf_rne(v.x); u.y = f2bf_rne(v.y);
        u.z = f2bf_rne(v.z); u.w = f2bf_rne(v.w);
        ((ushort4*)dst_bf)[(size_t)b * 4096 + p] = u;
    }
}

// ---- exact score, bit-identical to r2 (final-decision arithmetic) ----
__device__ float exact_score(const float* __restrict__ xr, const float* __restrict__ er,
                             float nx2r, float ne2v) {
    float a = 0.f;
    for (int d = 0; d < DIM; d += 16) {
        float4 xa = *(const float4*)(xr + d);
        float4 xb = *(const float4*)(xr + d + 4);
        float4 xc = *(const float4*)(xr + d + 8);
        float4 xd = *(const float4*)(xr + d + 12);
        float4 e0 = *(const float4*)(er + d);
        float4 e1 = *(const float4*)(er + d + 4);
        float4 e2 = *(const float4*)(er + d + 8);
        float4 e3 = *(const float4*)(er + d + 12);
        a = fmaf(xa.x, e0.x, a); a = fmaf(xa.y, e0.y, a);
        a = fmaf(xa.z, e0.z, a); a = fmaf(xa.w, e0.w, a);
        a = fmaf(xb.x, e1.x, a); a = fmaf(xb.y, e1.y, a);
        a = fmaf(xb.z, e1.z, a); a = fmaf(xb.w, e1.w, a);
        a = fmaf(xc.x, e2.x, a); a = fmaf(xc.y, e2.y, a);
        a = fmaf(xc.z, e2.z, a); a = fmaf(xc.w, e2.w, a);
        a = fmaf(xd.x, e3.x, a); a = fmaf(xd.y, e3.y, a);
        a = fmaf(xd.z, e3.z, a); a = fmaf(xd.w, e3.w, a);
    }
    float t1 = __fadd_rn(nx2r, ne2v);
    return __fsub_rn(t1, __fmul_rn(2.f, a));
}

// ---- 16-element slice dot (fallback scorer) ----
__device__ __forceinline__ float slice_dot16(const float4* xv, const float* __restrict__ er) {
    float4 e0 = *(const float4*)(er);
    float4 e1 = *(const float4*)(er + 4);
    float4 e2 = *(const float4*)(er + 8);
    float4 e3 = *(const float4*)(er + 12);
    float a = 0.f;
    a = fmaf(xv[0].x, e0.x, a); a = fmaf(xv[0].y, e0.y, a);
    a = fmaf(xv[0].z, e0.z, a); a = fmaf(xv[0].w, e0.w, a);
    a = fmaf(xv[1].x, e1.x, a); a = fmaf(xv[1].y, e1.y, a);
    a = fmaf(xv[1].z, e1.z, a); a = fmaf(xv[1].w, e1.w, a);
    a = fmaf(xv[2].x, e2.x, a); a = fmaf(xv[2].y, e2.y, a);
    a = fmaf(xv[2].z, e2.z, a); a = fmaf(xv[2].w, e2.w, a);
    a = fmaf(xv[3].x, e3.x, a); a = fmaf(xv[3].y, e3.y, a);
    a = fmaf(xv[3].z, e3.z, a); a = fmaf(xv[3].w, e3.w, a);
    return a;
}

// ---- pass 1: 64-row x 128-code tiles, 3-buffer counted-vmcnt pipeline ----
__global__ __launch_bounds__(256, 2) void gemm_cand(
        const unsigned short* __restrict__ xbf,
        const unsigned short* __restrict__ cbbf,
        const float* __restrict__ ne2,
        unsigned* __restrict__ cand_cnt,
        unsigned* __restrict__ cand_ent,
        unsigned* __restrict__ ma_enc) {
    __shared__ __align__(16) char Bs[49152];             // 3 x 16KB B rotation / x-stage union
    __shared__ __align__(16) unsigned cand_lds[64][CAP]; // 24KB
    __shared__ unsigned rmin_u[64];
    __shared__ unsigned cnt_s[64];

    const int tid = threadIdx.x;
    const int w = tid >> 6, lane = tid & 63;
    const int wr = w >> 1, wc = w & 1;                   // 2x2 wave grid
    const size_t brow = (size_t)blockIdx.x * 64;
    const int srcoff = ((lane & 7) ^ (lane >> 3)) << 4;  // B-staging swizzle

    if (tid < 64) { rmin_u[tid] = 0xFFFFFFFFu; cnt_s[tid] = 0u; }

    // ---- prologue: stage x panel (64 rows x 512B, swizzled) then A frags ----
    #pragma unroll
    for (int i = 0; i < 8; ++i) {
        int chunk = w * 8 + i;                           // 0..31 (1KB = 2 rows)
        int rowg = chunk * 2 + (lane >> 5);
        int src16 = (lane & 31) ^ (rowg & 7);
        const char* ga = (const char*)xbf + (brow + rowg) * 512 + (src16 << 4);
        __builtin_amdgcn_global_load_lds(
            (const __attribute__((address_space(1))) unsigned*)ga,
            (__attribute__((address_space(3))) unsigned*)(Bs + chunk * 1024),
            16, 0, 0);
    }
    __syncthreads();
    bf16x8 af[2][8];
    #pragma unroll
    for (int m = 0; m < 2; ++m) {
        int r = wr * 32 + m * 16 + (lane & 15);
        #pragma unroll
        for (int ks = 0; ks < 8; ++ks) {
            int g = (ks * 4 + (lane >> 4)) ^ (r & 7);
            af[m][ks] = *(const bf16x8*)(Bs + r * 512 + (g << 4));
        }
    }
    __syncthreads();

    auto stageB = [&](int buf, int ct, int tt) {
        #pragma unroll
        for (int i = 0; i < 4; ++i) {
            int chunk = w * 4 + i;                       // 0..15
            int code = ct * 128 + chunk * 8 + (lane >> 3);
            const char* gb = (const char*)cbbf + (size_t)code * 512 + tt * 128 + srcoff;
            __builtin_amdgcn_global_load_lds(
                (const __attribute__((address_space(1))) unsigned*)gb,
                (__attribute__((address_space(3))) unsigned*)(Bs + buf * 16384 + chunk * 1024),
                16, 0, 0);
        }
    };

    f32x4 acc[2][4];
    #pragma unroll
    for (int m = 0; m < 2; ++m)
        #pragma unroll
        for (int n = 0; n < 4; ++n) acc[m][n] = (f32x4){0.f, 0.f, 0.f, 0.f};

    // steps s = ct*4 + tt; buffer s%3; staged at step s-1 (depth-1).
    int cur = 0, nxt = 1;
    stageB(0, 0, 0);

    #pragma unroll 4
    for (int s = 0; s < 128; ++s) {
        const int tt = s & 3;
        // hoist ne2h loads above the stage issue so the compiler's wait for
        // them (in the epilogue) doesn't drain the prefetch (vmcnt in-order).
        float ne2h[4];
        if (tt == 3) {
            const int ct = s >> 2;
            #pragma unroll
            for (int n = 0; n < 4; ++n)
                ne2h[n] = 0.5f * ne2[ct * 128 + wc * 64 + n * 16 + (lane & 15)];
        }
        if (s < 127) {
            const int s1 = s + 1;
            stageB(nxt, s1 >> 2, s1 & 3);
        }
        if (s < 127) asm volatile("s_waitcnt vmcnt(4)" ::: "memory");
        else         asm volatile("s_waitcnt vmcnt(0)" ::: "memory");
        __builtin_amdgcn_s_barrier();
        __builtin_amdgcn_sched_barrier(0);

        #pragma unroll
        for (int kk = 0; kk < 2; ++kk) {
            bf16x8 bg[4];
            #pragma unroll
            for (int n = 0; n < 4; ++n) {
                int cc = wc * 64 + n * 16 + (lane & 15);
                int g = (kk * 4 + (lane >> 4)) ^ (cc & 7);
                bg[n] = *(const bf16x8*)(Bs + cur * 16384 + cc * 128 + (g << 4));
            }
            #pragma unroll
            for (int m = 0; m < 2; ++m)
                #pragma unroll
                for (int n = 0; n < 4; ++n)
                    acc[m][n] = __builtin_amdgcn_mfma_f32_16x16x32_bf16(
                        af[m][tt * 2 + kk], bg[n], acc[m][n], 0, 0, 0);
        }

        if (tt == 3) {
            // ---- barrier-free epilogue for col tile ct (128 codes) ----
            const int ct = s >> 2;
            #pragma unroll
            for (int m = 0; m < 2; ++m) {
                #pragma unroll
                for (int j = 0; j < 4; ++j) {
                    float v = fminf(fminf(ne2h[0] - acc[m][0][j], ne2h[1] - acc[m][1][j]),
                                    fminf(ne2h[2] - acc[m][2][j], ne2h[3] - acc[m][3][j]));
                    #pragma unroll
                    for (int off = 1; off < 16; off <<= 1)
                        v = fminf(v, __shfl_xor(v, off, 64));
                    const int rowl = wr * 32 + m * 16 + (lane >> 4) * 4 + j;
                    if ((lane & 15) == 0) atomicMin(&rmin_u[rowl], enc32(v));
                    // stale reads of rmin_u only loosen the threshold (superset).
                    float th = fminf(dec32(rmin_u[rowl]), v) + TAU_H;
                    #pragma unroll
                    for (int n = 0; n < 4; ++n) {
                        float sc = ne2h[n] - acc[m][n][j];
                        if (sc <= th) {
                            int col = ct * 128 + wc * 64 + n * 16 + (lane & 15);
                            int q = (int)rintf(sc * QSC) + 32768;
                            q = max(0, min(65535, q));
                            unsigned pos = atomicAdd(&cnt_s[rowl], 1u);
                            if (pos < CAP)
                                cand_lds[rowl][pos] = ((unsigned)q << 16) | (unsigned)col;
                        }
                    }
                    acc[m][0][j] = 0.f; acc[m][1][j] = 0.f;
                    acc[m][2][j] = 0.f; acc[m][3][j] = 0.f;
                }
            }
        }
        cur = nxt; nxt = (nxt + 1 == 3) ? 0 : nxt + 1;
    }

    // ---- single coalesced flush (uint4): 64*96*4B = 1536 uint4 ----
    __syncthreads();
    {
        uint4* dst = (uint4*)(cand_ent + brow * CAP);
        const uint4* srcl = (const uint4*)&cand_lds[0][0];
        #pragma unroll
        for (int k = 0; k < 6; ++k)
            dst[tid + k * 256] = srcl[tid + k * 256];
    }
    if (tid < 64) {
        cand_cnt[brow + tid] = cnt_s[tid];
        ma_enc[brow + tid] = rmin_u[tid];
    }
}

// ---- pass 2: exact refine (one wave per row, q16-prefiltered) ----
__global__ __launch_bounds__(256) void refine_kernel(
        const float* __restrict__ x, const float* __restrict__ cb,
        const float* __restrict__ ne2, const float* __restrict__ nx2,
        const unsigned* __restrict__ cand_cnt,
        const unsigned* __restrict__ cand_ent,
        const unsigned* __restrict__ ma_enc,
        float* __restrict__ out_idx, int* __restrict__ counts) {
    const int wid = threadIdx.x >> 6;
    const size_t row = (size_t)blockIdx.x * 4 + wid;
    const int lane = threadIdx.x & 63;
    const unsigned cnt = cand_cnt[row];
    const float nx2r = nx2[row];
    const float* xr = x + row * DIM;
    unsigned long long best = ~0ull;

    if (cnt <= CAP) {
        float mav = dec32(ma_enc[row]);
        int qthr = (int)rintf((mav + TAU_H) * QSC) + 1 + 32768;
        for (unsigned p = lane; p < cnt; p += 64) {
            unsigned e = cand_ent[row * CAP + p];
            if ((int)(e >> 16) <= qthr) {
                int code = (int)(e & 0xFFFFu);
                float s = exact_score(xr, cb + (size_t)code * DIM, nx2r, ne2[code]);
                unsigned long long pk = ((unsigned long long)enc32(s) << 32) | (unsigned)code;
                best = best < pk ? best : pk;
            }
        }
    }
    #pragma unroll
    for (int off = 1; off < 64; off <<= 1) {
        unsigned long long o = __shfl_xor(best, off, 64);
        best = best < o ? best : o;
    }
    if (best == ~0ull) {   // overflow / empty: full scan (tree prefilter + exact)
        const int g = lane >> 4, e = lane & 15;
        float4 xv[4];
        {
            const float4* xp = (const float4*)(xr + e * 16);
            xv[0] = xp[0]; xv[1] = xp[1]; xv[2] = xp[2]; xv[3] = xp[3];
        }
        float mt = INFINITY;
        for (int base = 0; base < NUM_EMB; base += 4) {
            int code = base + g;
            float d = slice_dot16(xv, cb + (size_t)code * DIM + e * 16);
            d += __shfl_xor(d, 1); d += __shfl_xor(d, 2);
            d += __shfl_xor(d, 4); d += __shfl_xor(d, 8);
            float s = __fsub_rn(__fadd_rn(nx2r, ne2[code]), __fmul_rn(2.f, d));
            mt = fminf(mt, s);
        }
        mt = fminf(mt, __shfl_xor(mt, 16));
        mt = fminf(mt, __shfl_xor(mt, 32));
        const float thr = mt + EPS_T;
        unsigned long long b2 = ~0ull;
        for (int base = 0; base < NUM_EMB; base += 4) {
            int code = base + g;
            float d = slice_dot16(xv, cb + (size_t)code * DIM + e * 16);
            d += __shfl_xor(d, 1); d += __shfl_xor(d, 2);
            d += __shfl_xor(d, 4); d += __shfl_xor(d, 8);
            float s = __fsub_rn(__fadd_rn(nx2r, ne2[code]), __fmul_rn(2.f, d));
            if (s <= thr && e == 0) {
                float se = exact_score(xr, cb + (size_t)code * DIM, nx2r, ne2[code]);
                unsigned long long pk = ((unsigned long long)enc32(se) << 32) | (unsigned)code;
                b2 = b2 < pk ? b2 : pk;
            }
        }
        #pragma unroll
        for (int off = 1; off < 64; off <<= 1) {
            unsigned long long o = __shfl_xor(b2, off, 64);
            b2 = b2 < o ? b2 : o;
        }
        best = b2;
    }
    if (lane == 0) {
        int idx = (int)(best & 0xFFFFFFFFull);
        idx = max(0, min(NUM_EMB - 1, idx));
        out_idx[row] = (float)idx;
        atomicAdd(&counts[idx], 1);
    }
}

// ---- pass 3: gather quantized + loss partials ----
__global__ __launch_bounds__(256) void outputs_kernel(
        const float* __restrict__ x, const float* __restrict__ cb,
        const float* __restrict__ out_idx, float* __restrict__ out_q,
        float* __restrict__ partials) {
    __shared__ float red[256];
    const int t = threadIdx.x, b = blockIdx.x;
    const size_t rowbase = (size_t)b * 64;
    const int r = t >> 2, c0 = (t & 3) * 16;
    const size_t row = rowbase + r;
    int qi = (int)out_idx[row];
    qi = max(0, min(NUM_EMB - 1, qi));
    const float4* crq = (const float4*)(cb + (size_t)qi * DIM);
    const float4* xr4 = (const float4*)(x + row * DIM);
    float4* oq = (float4*)(out_q + row * DIM);
    float ss = 0.f;
    #pragma unroll
    for (int k = 0; k < 16; ++k) {
        float4 q = crq[c0 + k];
        float4 xv = xr4[c0 + k];
        oq[c0 + k] = q;
        float dx = xv.x - q.x, dy = xv.y - q.y, dz = xv.z - q.z, dw = xv.w - q.w;
        ss += dx * dx + dy * dy + dz * dz + dw * dw;
    }
    red[t] = ss; __syncthreads();
    for (int st = 128; st; st >>= 1) {
        if (t < st) red[t] += red[t + st];
        __syncthreads();
    }
    if (t == 0) partials[b] = red[0];
}

__global__ void finalize_kernel(const float* __restrict__ partials, int np,
                                const int* __restrict__ counts,
                                float* __restrict__ out_loss,
                                float* __restrict__ out_perp) {
    __shared__ double sh[256];
    const int t = threadIdx.x;
    double s = 0.0;
    for (int i = t; i < np; i += 256) s += (double)partials[i];
    sh[t] = s; __syncthreads();
    for (int st = 128; st; st >>= 1) { if (t < st) sh[t] += sh[t + st]; __syncthreads(); }
    double sse = sh[0];
    __syncthreads();
    double h = 0.0;
    for (int k = t; k < NUM_EMB; k += 256) {
        double p = (double)counts[k] / (double)N_INPUTS;
        h -= p * log(p + 1e-10);
    }
    sh[t] = h; __syncthreads();
    for (int st = 128; st; st >>= 1) { if (t < st) sh[t] += sh[t + st]; __syncthreads(); }
    if (t == 0) {
        double mse = sse / ((double)N_INPUTS * (double)DIM);
        out_loss[0] = (float)(1.25 * mse);
        out_perp[0] = (float)exp(sh[0]);
    }
}

extern "C" void kernel_launch(void* const* d_in, const int* in_sizes, int n_in,
                              void* d_out, int out_size, void* d_ws, size_t ws_size,
                              hipStream_t stream) {
    const float* x  = (const float*)d_in[0];
    const float* cb = (const float*)d_in[1];
    float* out      = (float*)d_out;

    float* out_q    = out;                           // 16777216 f32 (64 MiB)
    float* out_loss = out + (size_t)N_INPUTS * DIM;
    float* out_perp = out_loss + 1;
    float* out_idx  = out_perp + 1;

    // scratch inside out_q region (rewritten by outputs_kernel at the end)
    char* sc = (char*)out_q;
    unsigned short* cbbf = (unsigned short*)(sc);                   // 2 MB @0
    unsigned short* xbf  = (unsigned short*)(sc + 2097152);         // 32 MB @2MB
    unsigned* cand_ent   = (unsigned*)(sc + 35651584);              // 24 MB @34MB
    unsigned* cand_cnt   = (unsigned*)(sc + 60817408);              // 256 KB @58MB
    unsigned* ma_enc     = (unsigned*)(sc + 61079552);              // 256 KB

    float* ne2      = (float*)d_ws;                       // 16 KB
    int*   counts   = (int*)((char*)d_ws + 16384);        // 16 KB
    float* partials = (float*)((char*)d_ws + 32768);      // 4 KB
    float* nx2      = (float*)((char*)d_ws + 36864);      // 256 KB

    hipMemsetAsync(counts, 0, NUM_EMB * sizeof(int), stream);

    prep_rows<<<NUM_EMB / 64, 256, 0, stream>>>(cb, ne2, cbbf);
    prep_rows<<<N_INPUTS / 64, 256, 0, stream>>>(x, nx2, xbf);

    gemm_cand<<<N_INPUTS / 64, 256, 0, stream>>>(xbf, cbbf, ne2, cand_cnt,
                                                 cand_ent, ma_enc);
    refine_kernel<<<N_INPUTS / 4, 256, 0, stream>>>(x, cb, ne2, nx2, cand_cnt, cand_ent,
                                                    ma_enc, out_idx, counts);
    outputs_kernel<<<N_INPUTS / 64, 256, 0, stream>>>(x, cb, out_idx, out_q, partials);
    finalize_kernel<<<1, 256, 0, stream>>>(partials, N_INPUTS / 64, counts,
                                           out_loss, out_perp);
}

// Round 14
// 612.342 us; speedup vs baseline: 1.1642x; 1.0613x over previous
//
#include <hip/hip_runtime.h>
#include <hip/hip_bf16.h>
#include <math.h>

#define N_INPUTS 65536
#define NUM_EMB 4096
#define DIM 256
#define TAU_H 9.0e-4f     // half-score threshold (empirically validated r4-r13)
#define CAP 95
#define QSC 1.0e6f
#define EPS_T 1.0e-4f     // tree-vs-serial dot guard (fallback only)

typedef __attribute__((ext_vector_type(8))) short bf16x8;
typedef __attribute__((ext_vector_type(4))) float f32x4;

// ---- monotone float<->uint packing ----
__device__ __forceinline__ unsigned enc32(float f) {
    unsigned u = __float_as_uint(f);
    return (u & 0x80000000u) ? ~u : (u | 0x80000000u);
}
__device__ __forceinline__ float dec32(unsigned e) {
    unsigned u = (e & 0x80000000u) ? (e & 0x7FFFFFFFu) : ~e;
    return __uint_as_float(u);
}
__device__ __forceinline__ unsigned short f2bf_rne(float f) {
    unsigned u = __float_as_uint(f);
    return (unsigned short)((u + 0x7FFFu + ((u >> 16) & 1u)) >> 16);
}

// ---- numpy pairwise sum of squares (bit-exact, proven r2) ----
__device__ __forceinline__ float pw128_sq(const float* __restrict__ a) {
    float r[8];
    #pragma unroll
    for (int j = 0; j < 8; ++j) r[j] = __fmul_rn(a[j], a[j]);
    #pragma unroll
    for (int i = 8; i < 128; i += 8)
        #pragma unroll
        for (int j = 0; j < 8; ++j)
            r[j] = __fadd_rn(r[j], __fmul_rn(a[i + j], a[i + j]));
    return __fadd_rn(__fadd_rn(__fadd_rn(r[0], r[1]), __fadd_rn(r[2], r[3])),
                     __fadd_rn(__fadd_rn(r[4], r[5]), __fadd_rn(r[6], r[7])));
}
__device__ __forceinline__ float pw256_sq(const float* __restrict__ a) {
    return __fadd_rn(pw128_sq(a), pw128_sq(a + 128));
}

// ---- prep (codebook): norms + bf16 copy into out-row TAILS (row*1024+384) ----
__global__ __launch_bounds__(256) void prep_cb(
        const float* __restrict__ src, float* __restrict__ norms,
        char* dst_base) {
    __shared__ float xs[64 * 260];
    const int t = threadIdx.x, b = blockIdx.x;
    const size_t rowbase = (size_t)b * 64;
    const float4* g = (const float4*)(src + rowbase * DIM);
    float4* s4 = (float4*)xs;
    #pragma unroll
    for (int k = 0; k < 16; ++k) {
        int p = t + k * 256, r = p >> 6, c = p & 63;
        s4[r * 65 + c] = g[p];
    }
    __syncthreads();
    if (t < 64) norms[rowbase + t] = pw256_sq(xs + t * 260);
    #pragma unroll
    for (int k = 0; k < 16; ++k) {
        int p = t + k * 256, r = p >> 6, c = p & 63;
        float4 v = s4[r * 65 + c];
        ushort4 u;
        u.x = f2bf_rne(v.x); u.y = f2bf_rne(v.y);
        u.z = f2bf_rne(v.z); u.w = f2bf_rne(v.w);
        ((ushort4*)(dst_base + (rowbase + r) * 1024 + 384))[c] = u;
    }
}

// ---- exact score, bit-identical to r2 (final-decision arithmetic) ----
__device__ float exact_score(const float* __restrict__ xr, const float* __restrict__ er,
                             float nx2r, float ne2v) {
    float a = 0.f;
    for (int d = 0; d < DIM; d += 16) {
        float4 xa = *(const float4*)(xr + d);
        float4 xb = *(const float4*)(xr + d + 4);
        float4 xc = *(const float4*)(xr + d + 8);
        float4 xd = *(const float4*)(xr + d + 12);
        float4 e0 = *(const float4*)(er + d);
        float4 e1 = *(const float4*)(er + d + 4);
        float4 e2 = *(const float4*)(er + d + 8);
        float4 e3 = *(const float4*)(er + d + 12);
        a = fmaf(xa.x, e0.x, a); a = fmaf(xa.y, e0.y, a);
        a = fmaf(xa.z, e0.z, a); a = fmaf(xa.w, e0.w, a);
        a = fmaf(xb.x, e1.x, a); a = fmaf(xb.y, e1.y, a);
        a = fmaf(xb.z, e1.z, a); a = fmaf(xb.w, e1.w, a);
        a = fmaf(xc.x, e2.x, a); a = fmaf(xc.y, e2.y, a);
        a = fmaf(xc.z, e2.z, a); a = fmaf(xc.w, e2.w, a);
        a = fmaf(xd.x, e3.x, a); a = fmaf(xd.y, e3.y, a);
        a = fmaf(xd.z, e3.z, a); a = fmaf(xd.w, e3.w, a);
    }
    float t1 = __fadd_rn(nx2r, ne2v);
    return __fsub_rn(t1, __fmul_rn(2.f, a));
}

// ---- 16-element slice dot (fallback scorer) ----
__device__ __forceinline__ float slice_dot16(const float4* xv, const float* __restrict__ er) {
    float4 e0 = *(const float4*)(er);
    float4 e1 = *(const float4*)(er + 4);
    float4 e2 = *(const float4*)(er + 8);
    float4 e3 = *(const float4*)(er + 12);
    float a = 0.f;
    a = fmaf(xv[0].x, e0.x, a); a = fmaf(xv[0].y, e0.y, a);
    a = fmaf(xv[0].z, e0.z, a); a = fmaf(xv[0].w, e0.w, a);
    a = fmaf(xv[1].x, e1.x, a); a = fmaf(xv[1].y, e1.y, a);
    a = fmaf(xv[1].z, e1.z, a); a = fmaf(xv[1].w, e1.w, a);
    a = fmaf(xv[2].x, e2.x, a); a = fmaf(xv[2].y, e2.y, a);
    a = fmaf(xv[2].z, e2.z, a); a = fmaf(xv[2].w, e2.w, a);
    a = fmaf(xv[3].x, e3.x, a); a = fmaf(xv[3].y, e3.y, a);
    a = fmaf(xv[3].z, e3.z, a); a = fmaf(xv[3].w, e3.w, a);
    return a;
}

// ---- pass 1: x-prep folded in; 3-buffer counted-vmcnt MFMA pipeline;
// candidates flushed into each row's OWN out_q slot (no cross-block hazard).
__global__ __launch_bounds__(256, 2) void gemm_cand(
        const float* __restrict__ x,
        const char* cbB,              // = (char*)out + 384, stride 1024/row
        const float* __restrict__ ne2,
        unsigned* outw,               // u32 view of out base (cand slots)
        unsigned* cntreg,             // cnt per row (out_idx region)
        float* __restrict__ nx2) {
    __shared__ __align__(16) char Bs[49152];             // 3 x 16KB B rot / x-stage union
    __shared__ __align__(16) unsigned cand_lds[64][CAP]; // 23.75KB
    __shared__ unsigned rmin_u[64];
    __shared__ unsigned cnt_s[64];

    const int tid = threadIdx.x;
    const int w = tid >> 6, lane = tid & 63;
    const int wr = w >> 1, wc = w & 1;                   // 2x2 wave grid
    const size_t brow = (size_t)blockIdx.x * 64;
    const int srcoff = ((lane & 7) ^ (lane >> 3)) << 4;  // B-staging swizzle

    if (tid < 64) { rmin_u[tid] = 0xFFFFFFFFu; cnt_s[tid] = 0u; }

    // ---- prologue: stage x f32 in 2 halves of 32 rows; norms + A frags ----
    bf16x8 af[2][8];
    float* xs = (float*)Bs;                              // padded [32][260]
    #pragma unroll
    for (int h = 0; h < 2; ++h) {
        const float4* g = (const float4*)(x + (brow + (size_t)h * 32) * DIM);
        #pragma unroll
        for (int r = 0; r < 8; ++r) {
            int p = tid + r * 256, rr = p >> 6, c = p & 63;
            ((float4*)xs)[rr * 65 + c] = g[p];
        }
        __syncthreads();
        if (tid < 32) nx2[brow + h * 32 + tid] = pw256_sq(xs + tid * 260);
        if (wr == h) {
            #pragma unroll
            for (int m = 0; m < 2; ++m) {
                #pragma unroll
                for (int ks = 0; ks < 8; ++ks) {
                    const float* rp = xs + (m * 16 + (lane & 15)) * 260
                                      + ks * 32 + (lane >> 4) * 8;
                    float4 a = *(const float4*)rp, b = *(const float4*)(rp + 4);
                    bf16x8 v;
                    v[0] = (short)f2bf_rne(a.x); v[1] = (short)f2bf_rne(a.y);
                    v[2] = (short)f2bf_rne(a.z); v[3] = (short)f2bf_rne(a.w);
                    v[4] = (short)f2bf_rne(b.x); v[5] = (short)f2bf_rne(b.y);
                    v[6] = (short)f2bf_rne(b.z); v[7] = (short)f2bf_rne(b.w);
                    af[m][ks] = v;
                }
            }
        }
        __syncthreads();
    }

    auto stageB = [&](int buf, int ct, int tt) {
        #pragma unroll
        for (int i = 0; i < 4; ++i) {
            int chunk = w * 4 + i;                       // 0..15
            int code = ct * 128 + chunk * 8 + (lane >> 3);
            const char* gb = cbB + (size_t)code * 1024 + tt * 128 + srcoff;
            __builtin_amdgcn_global_load_lds(
                (const __attribute__((address_space(1))) unsigned*)gb,
                (__attribute__((address_space(3))) unsigned*)(Bs + buf * 16384 + chunk * 1024),
                16, 0, 0);
        }
    };

    f32x4 acc[2][4];
    #pragma unroll
    for (int m = 0; m < 2; ++m)
        #pragma unroll
        for (int n = 0; n < 4; ++n) acc[m][n] = (f32x4){0.f, 0.f, 0.f, 0.f};

    // steps s = ct*4 + tt; buffer s%3; staged at step s-1 (depth-1).
    int cur = 0, nxt = 1;
    stageB(0, 0, 0);

    #pragma unroll 4
    for (int s = 0; s < 128; ++s) {
        const int tt = s & 3;
        float ne2h[4];
        if (tt == 3) {                                   // hoist above stage issue
            const int ct = s >> 2;
            #pragma unroll
            for (int n = 0; n < 4; ++n)
                ne2h[n] = 0.5f * ne2[ct * 128 + wc * 64 + n * 16 + (lane & 15)];
        }
        if (s < 127) {
            const int s1 = s + 1;
            stageB(nxt, s1 >> 2, s1 & 3);
        }
        if (s < 127) asm volatile("s_waitcnt vmcnt(4)" ::: "memory");
        else         asm volatile("s_waitcnt vmcnt(0)" ::: "memory");
        __builtin_amdgcn_s_barrier();
        __builtin_amdgcn_sched_barrier(0);

        #pragma unroll
        for (int kk = 0; kk < 2; ++kk) {
            bf16x8 bg[4];
            #pragma unroll
            for (int n = 0; n < 4; ++n) {
                int cc = wc * 64 + n * 16 + (lane & 15);
                int g = (kk * 4 + (lane >> 4)) ^ (cc & 7);
                bg[n] = *(const bf16x8*)(Bs + cur * 16384 + cc * 128 + (g << 4));
            }
            #pragma unroll
            for (int m = 0; m < 2; ++m)
                #pragma unroll
                for (int n = 0; n < 4; ++n)
                    acc[m][n] = __builtin_amdgcn_mfma_f32_16x16x32_bf16(
                        af[m][tt * 2 + kk], bg[n], acc[m][n], 0, 0, 0);
        }

        if (tt == 3) {
            // ---- barrier-free epilogue for col tile ct (128 codes) ----
            const int ct = s >> 2;
            #pragma unroll
            for (int m = 0; m < 2; ++m) {
                #pragma unroll
                for (int j = 0; j < 4; ++j) {
                    float v = fminf(fminf(ne2h[0] - acc[m][0][j], ne2h[1] - acc[m][1][j]),
                                    fminf(ne2h[2] - acc[m][2][j], ne2h[3] - acc[m][3][j]));
                    #pragma unroll
                    for (int off = 1; off < 16; off <<= 1)
                        v = fminf(v, __shfl_xor(v, off, 64));
                    const int rowl = wr * 32 + m * 16 + (lane >> 4) * 4 + j;
                    if ((lane & 15) == 0) atomicMin(&rmin_u[rowl], enc32(v));
                    // stale reads of rmin_u only loosen the threshold (superset).
                    float th = fminf(dec32(rmin_u[rowl]), v) + TAU_H;
                    #pragma unroll
                    for (int n = 0; n < 4; ++n) {
                        float sc = ne2h[n] - acc[m][n][j];
                        if (sc <= th) {
                            int col = ct * 128 + wc * 64 + n * 16 + (lane & 15);
                            int q = (int)rintf(sc * QSC) + 32768;
                            q = max(0, min(65535, q));
                            unsigned pos = atomicAdd(&cnt_s[rowl], 1u);
                            if (pos < CAP)
                                cand_lds[rowl][pos] = ((unsigned)q << 16) | (unsigned)col;
                        }
                    }
                    acc[m][0][j] = 0.f; acc[m][1][j] = 0.f;
                    acc[m][2][j] = 0.f; acc[m][3][j] = 0.f;
                }
            }
        }
        cur = nxt; nxt = (nxt + 1 == 3) ? 0 : nxt + 1;
    }

    // ---- flush [ma | 95 entries] into each row's OWN out slot ----
    __syncthreads();
    for (int i = tid; i < 64 * 96; i += 256) {
        int row = i / 96, sl = i - row * 96;
        unsigned v = (sl == 0) ? rmin_u[row] : cand_lds[row][sl - 1];
        outw[(brow + row) * 256 + sl] = v;
    }
    if (tid < 64) cntreg[brow + tid] = cnt_s[tid];
}

// ---- pass 2: fused refine + quantized write + loss partial (1 wave/row) ----
__global__ __launch_bounds__(256) void refine_outputs(
        const float* __restrict__ x, const float* __restrict__ cb,
        const float* __restrict__ ne2, const float* __restrict__ nx2,
        float* out,                  // base (cand slots read, quantized written)
        unsigned* cntreg,            // cnt per row; overwritten with idx (float)
        int* __restrict__ counts, float* __restrict__ partials) {
    __shared__ float red[4];
    const int wid = threadIdx.x >> 6, lane = threadIdx.x & 63;
    const size_t row = (size_t)blockIdx.x * 4 + wid;
    const unsigned cnt = cntreg[row];
    const unsigned* slot = (const unsigned*)out + row * 256;
    const float nx2r = nx2[row];
    const float* xr = x + row * DIM;
    unsigned long long best = ~0ull;

    if (cnt <= CAP) {
        float mav = dec32(slot[0]);
        int qthr = (int)rintf((mav + TAU_H) * QSC) + 1 + 32768;
        for (unsigned p = lane; p < cnt; p += 64) {
            unsigned e = slot[1 + p];
            if ((int)(e >> 16) <= qthr) {
                int code = (int)(e & 0xFFFFu);
                float s = exact_score(xr, cb + (size_t)code * DIM, nx2r, ne2[code]);
                unsigned long long pk = ((unsigned long long)enc32(s) << 32) | (unsigned)code;
                best = best < pk ? best : pk;
            }
        }
    }
    #pragma unroll
    for (int off = 1; off < 64; off <<= 1) {
        unsigned long long o = __shfl_xor(best, off, 64);
        best = best < o ? best : o;
    }
    if (best == ~0ull) {   // overflow / empty: full scan (tree prefilter + exact)
        const int g = lane >> 4, e = lane & 15;
        float4 xv[4];
        {
            const float4* xp = (const float4*)(xr + e * 16);
            xv[0] = xp[0]; xv[1] = xp[1]; xv[2] = xp[2]; xv[3] = xp[3];
        }
        float mt = INFINITY;
        for (int base = 0; base < NUM_EMB; base += 4) {
            int code = base + g;
            float d = slice_dot16(xv, cb + (size_t)code * DIM + e * 16);
            d += __shfl_xor(d, 1); d += __shfl_xor(d, 2);
            d += __shfl_xor(d, 4); d += __shfl_xor(d, 8);
            float s = __fsub_rn(__fadd_rn(nx2r, ne2[code]), __fmul_rn(2.f, d));
            mt = fminf(mt, s);
        }
        mt = fminf(mt, __shfl_xor(mt, 16));
        mt = fminf(mt, __shfl_xor(mt, 32));
        const float thr = mt + EPS_T;
        unsigned long long b2 = ~0ull;
        for (int base = 0; base < NUM_EMB; base += 4) {
            int code = base + g;
            float d = slice_dot16(xv, cb + (size_t)code * DIM + e * 16);
            d += __shfl_xor(d, 1); d += __shfl_xor(d, 2);
            d += __shfl_xor(d, 4); d += __shfl_xor(d, 8);
            float s = __fsub_rn(__fadd_rn(nx2r, ne2[code]), __fmul_rn(2.f, d));
            if (s <= thr && e == 0) {
                float se = exact_score(xr, cb + (size_t)code * DIM, nx2r, ne2[code]);
                unsigned long long pk = ((unsigned long long)enc32(se) << 32) | (unsigned)code;
                b2 = b2 < pk ? b2 : pk;
            }
        }
        #pragma unroll
        for (int off = 1; off < 64; off <<= 1) {
            unsigned long long o = __shfl_xor(b2, off, 64);
            b2 = b2 < o ? b2 : o;
        }
        best = b2;
    }
    int idx = (int)(best & 0xFFFFFFFFull);
    idx = max(0, min(NUM_EMB - 1, idx));

    // ---- quantized write (overwrites this row's cand slot) + SSE ----
    float4 qv = *(const float4*)(cb + (size_t)idx * DIM + lane * 4);
    float4 xv4 = *(const float4*)(xr + lane * 4);
    *(float4*)(out + row * 256 + lane * 4) = qv;
    float dx = xv4.x - qv.x, dy = xv4.y - qv.y, dz = xv4.z - qv.z, dw = xv4.w - qv.w;
    float ss = dx * dx + dy * dy + dz * dz + dw * dw;
    #pragma unroll
    for (int off = 1; off < 64; off <<= 1) ss += __shfl_xor(ss, off, 64);
    if (lane == 0) {
        ((float*)cntreg)[row] = (float)idx;    // overwrites cnt (already read)
        atomicAdd(&counts[idx], 1);
        red[wid] = ss;
    }
    __syncthreads();
    if (threadIdx.x == 0)
        partials[blockIdx.x] = (red[0] + red[1]) + (red[2] + red[3]);
}

__global__ void finalize_kernel(const float* __restrict__ partials, int np,
                                const int* __restrict__ counts,
                                float* __restrict__ out_loss,
                                float* __restrict__ out_perp) {
    __shared__ double sh[256];
    const int t = threadIdx.x;
    double s = 0.0;
    for (int i = t; i < np; i += 256) s += (double)partials[i];
    sh[t] = s; __syncthreads();
    for (int st = 128; st; st >>= 1) { if (t < st) sh[t] += sh[t + st]; __syncthreads(); }
    double sse = sh[0];
    __syncthreads();
    double h = 0.0;
    for (int k = t; k < NUM_EMB; k += 256) {
        double p = (double)counts[k] / (double)N_INPUTS;
        h -= p * log(p + 1e-10);
    }
    sh[t] = h; __syncthreads();
    for (int st = 128; st; st >>= 1) { if (t < st) sh[t] += sh[t + st]; __syncthreads(); }
    if (t == 0) {
        double mse = sse / ((double)N_INPUTS * (double)DIM);
        out_loss[0] = (float)(1.25 * mse);
        out_perp[0] = (float)exp(sh[0]);
    }
}

extern "C" void kernel_launch(void* const* d_in, const int* in_sizes, int n_in,
                              void* d_out, int out_size, void* d_ws, size_t ws_size,
                              hipStream_t stream) {
    const float* x  = (const float*)d_in[0];
    const float* cb = (const float*)d_in[1];
    float* out      = (float*)d_out;

    float* out_q    = out;                              // 16777216 f32 (64 MiB)
    float* out_loss = out + (size_t)N_INPUTS * DIM;     // +16777216
    float* out_perp = out_loss + 1;
    unsigned* cntreg = (unsigned*)(out_perp + 1);       // out_idx region (cnt -> idx)

    // ws: ne2 16K | counts 16K | nx2 256K | partials 64K  (= 352 KB)
    float* ne2      = (float*)d_ws;
    int*   counts   = (int*)((char*)d_ws + 16384);
    float* nx2      = (float*)((char*)d_ws + 32768);
    float* partials = (float*)((char*)d_ws + 294912);

    hipMemsetAsync(counts, 0, NUM_EMB * sizeof(int), stream);

    // codebook: norms + bf16 into out-row tails (rows 0..4095, bytes +384..896)
    prep_cb<<<NUM_EMB / 64, 256, 0, stream>>>(cb, ne2, (char*)out);

    gemm_cand<<<N_INPUTS / 64, 256, 0, stream>>>(
        x, (const char*)out + 384, ne2, (unsigned*)out, cntreg, nx2);

    refine_outputs<<<N_INPUTS / 4, 256, 0, stream>>>(
        x, cb, ne2, nx2, out, cntreg, counts, partials);

    finalize_kernel<<<1, 256, 0, stream>>>(partials, N_INPUTS / 4, counts,
                                           out_loss, out_perp);
}

// Round 15
// 414.482 us; speedup vs baseline: 1.7199x; 1.4774x over previous
//
#include <hip/hip_runtime.h>
#include <hip/hip_bf16.h>
#include <math.h>

#define N_INPUTS 65536
#define NUM_EMB 4096
#define DIM 256
#define TAU_H 9.0e-4f     // half-score threshold (empirically validated r4-r14)
#define CAP 120
#define QSC 1.0e6f
#define WLCAP 1536

// ---- unified LDS layout (bytes) ----
#define OFF_B    0        // main loop: 3 x 16KB B tiles / prologue x-stage [32][260]
#define OFF_CAND 49152    // 64 x CAP u32 = 30720
#define OFF_RMIN 79872    // 64 u32
#define OFF_CNT  80128    // 64 u32
#define OFF_NX2  80384    // 64 f32
#define OFF_WLC  80640    // u32 (+pad)
#define LDS_SZ   80704
// post-loop overlays (B/cand regions are dead):
#define OFF_WL   0        // u64[WLCAP] = 12288
#define OFF_X    12288    // [64][260] f32 = 66560 (ends 78848)
#define OFF_BST  78848    // 64 u32
#define OFF_BIX  79104    // 64 u32
#define OFF_RED  0        // f32[256] (after wl dead)

typedef __attribute__((ext_vector_type(8))) short bf16x8;
typedef __attribute__((ext_vector_type(4))) float f32x4;

__device__ __forceinline__ unsigned enc32(float f) {
    unsigned u = __float_as_uint(f);
    return (u & 0x80000000u) ? ~u : (u | 0x80000000u);
}
__device__ __forceinline__ float dec32(unsigned e) {
    unsigned u = (e & 0x80000000u) ? (e & 0x7FFFFFFFu) : ~e;
    return __uint_as_float(u);
}
__device__ __forceinline__ unsigned short f2bf_rne(float f) {
    unsigned u = __float_as_uint(f);
    return (unsigned short)((u + 0x7FFFu + ((u >> 16) & 1u)) >> 16);
}

// ---- numpy pairwise sum of squares (bit-exact, proven r2) ----
__device__ __forceinline__ float pw128_sq(const float* __restrict__ a) {
    float r[8];
    #pragma unroll
    for (int j = 0; j < 8; ++j) r[j] = __fmul_rn(a[j], a[j]);
    #pragma unroll
    for (int i = 8; i < 128; i += 8)
        #pragma unroll
        for (int j = 0; j < 8; ++j)
            r[j] = __fadd_rn(r[j], __fmul_rn(a[i + j], a[i + j]));
    return __fadd_rn(__fadd_rn(__fadd_rn(r[0], r[1]), __fadd_rn(r[2], r[3])),
                     __fadd_rn(__fadd_rn(r[4], r[5]), __fadd_rn(r[6], r[7])));
}
__device__ __forceinline__ float pw256_sq(const float* __restrict__ a) {
    return __fadd_rn(pw128_sq(a), pw128_sq(a + 128));
}

// ---- prep (codebook): norms + bf16 copy into out-row TAILS (row*1024+384) ----
__global__ __launch_bounds__(256) void prep_cb(
        const float* __restrict__ src, float* __restrict__ norms,
        char* dst_base) {
    __shared__ float xs[64 * 260];
    const int t = threadIdx.x, b = blockIdx.x;
    const size_t rowbase = (size_t)b * 64;
    const float4* g = (const float4*)(src + rowbase * DIM);
    float4* s4 = (float4*)xs;
    #pragma unroll
    for (int k = 0; k < 16; ++k) {
        int p = t + k * 256, r = p >> 6, c = p & 63;
        s4[r * 65 + c] = g[p];
    }
    __syncthreads();
    if (t < 64) norms[rowbase + t] = pw256_sq(xs + t * 260);
    #pragma unroll
    for (int k = 0; k < 16; ++k) {
        int p = t + k * 256, r = p >> 6, c = p & 63;
        float4 v = s4[r * 65 + c];
        ushort4 u;
        u.x = f2bf_rne(v.x); u.y = f2bf_rne(v.y);
        u.z = f2bf_rne(v.z); u.w = f2bf_rne(v.w);
        ((ushort4*)(dst_base + (rowbase + r) * 1024 + 384))[c] = u;
    }
}

// ---- exact score, bit-identical to r2 (final-decision arithmetic) ----
__device__ float exact_score(const float* xr, const float* __restrict__ er,
                             float nx2r, float ne2v) {
    float a = 0.f;
    for (int d = 0; d < DIM; d += 16) {
        float4 xa = *(const float4*)(xr + d);
        float4 xb = *(const float4*)(xr + d + 4);
        float4 xc = *(const float4*)(xr + d + 8);
        float4 xd = *(const float4*)(xr + d + 12);
        float4 e0 = *(const float4*)(er + d);
        float4 e1 = *(const float4*)(er + d + 4);
        float4 e2 = *(const float4*)(er + d + 8);
        float4 e3 = *(const float4*)(er + d + 12);
        a = fmaf(xa.x, e0.x, a); a = fmaf(xa.y, e0.y, a);
        a = fmaf(xa.z, e0.z, a); a = fmaf(xa.w, e0.w, a);
        a = fmaf(xb.x, e1.x, a); a = fmaf(xb.y, e1.y, a);
        a = fmaf(xb.z, e1.z, a); a = fmaf(xb.w, e1.w, a);
        a = fmaf(xc.x, e2.x, a); a = fmaf(xc.y, e2.y, a);
        a = fmaf(xc.z, e2.z, a); a = fmaf(xc.w, e2.w, a);
        a = fmaf(xd.x, e3.x, a); a = fmaf(xd.y, e3.y, a);
        a = fmaf(xd.z, e3.z, a); a = fmaf(xd.w, e3.w, a);
    }
    float t1 = __fadd_rn(nx2r, ne2v);
    return __fsub_rn(t1, __fmul_rn(2.f, a));
}

// ---- fused: gemm + candidates + in-block exact refine + outputs ----
__global__ __launch_bounds__(256, 2) void gemm_fused(
        const float* __restrict__ x,
        const char* cbB,              // bf16 codebook at (char*)out + 384, stride 1024
        const float* __restrict__ cb, // f32 codebook (input)
        const float* __restrict__ ne2,
        float* outp,                  // out base (quantized written if bid>=64)
        float* __restrict__ outidx,   // out_idx region
        int* __restrict__ counts, float* __restrict__ partials) {
    __shared__ __align__(16) char L[LDS_SZ];

    const int tid = threadIdx.x;
    const int w = tid >> 6, lane = tid & 63;
    const int wr = w >> 1, wc = w & 1;                   // 2x2 wave grid
    const size_t brow = (size_t)blockIdx.x * 64;
    const bool writeq = (blockIdx.x >= NUM_EMB / 64);
    const int srcoff = ((lane & 7) ^ (lane >> 3)) << 4;

    unsigned* rminp = (unsigned*)(L + OFF_RMIN);
    unsigned* cntp  = (unsigned*)(L + OFF_CNT);
    float*    nx2l  = (float*)(L + OFF_NX2);
    unsigned* wlcnt = (unsigned*)(L + OFF_WLC);
    unsigned (*cand)[CAP] = (unsigned (*)[CAP])(L + OFF_CAND);

    if (tid < 64) { rminp[tid] = 0xFFFFFFFFu; cntp[tid] = 0u; }
    if (tid == 64) *wlcnt = 0u;

    // ---- prologue: stage x f32 in 2 halves of 32 rows; norms + A frags ----
    bf16x8 af[2][8];
    float* xs = (float*)L;                               // [32][260]
    #pragma unroll
    for (int h = 0; h < 2; ++h) {
        const float4* g = (const float4*)(x + (brow + (size_t)h * 32) * DIM);
        #pragma unroll
        for (int r = 0; r < 8; ++r) {
            int p = tid + r * 256, rr = p >> 6, c = p & 63;
            ((float4*)xs)[rr * 65 + c] = g[p];
        }
        __syncthreads();
        if (tid < 32) nx2l[h * 32 + tid] = pw256_sq(xs + tid * 260);
        if (wr == h) {
            #pragma unroll
            for (int m = 0; m < 2; ++m) {
                #pragma unroll
                for (int ks = 0; ks < 8; ++ks) {
                    const float* rp = xs + (m * 16 + (lane & 15)) * 260
                                      + ks * 32 + (lane >> 4) * 8;
                    float4 a = *(const float4*)rp, b = *(const float4*)(rp + 4);
                    bf16x8 v;
                    v[0] = (short)f2bf_rne(a.x); v[1] = (short)f2bf_rne(a.y);
                    v[2] = (short)f2bf_rne(a.z); v[3] = (short)f2bf_rne(a.w);
                    v[4] = (short)f2bf_rne(b.x); v[5] = (short)f2bf_rne(b.y);
                    v[6] = (short)f2bf_rne(b.z); v[7] = (short)f2bf_rne(b.w);
                    af[m][ks] = v;
                }
            }
        }
        __syncthreads();
    }

    auto stageB = [&](int buf, int ct, int tt) {
        #pragma unroll
        for (int i = 0; i < 4; ++i) {
            int chunk = w * 4 + i;                       // 0..15
            int code = ct * 128 + chunk * 8 + (lane >> 3);
            const char* gb = cbB + (size_t)code * 1024 + tt * 128 + srcoff;
            __builtin_amdgcn_global_load_lds(
                (const __attribute__((address_space(1))) unsigned*)gb,
                (__attribute__((address_space(3))) unsigned*)(L + buf * 16384 + chunk * 1024),
                16, 0, 0);
        }
    };

    f32x4 acc[2][4];
    #pragma unroll
    for (int m = 0; m < 2; ++m)
        #pragma unroll
        for (int n = 0; n < 4; ++n) acc[m][n] = (f32x4){0.f, 0.f, 0.f, 0.f};

    int cur = 0, nxt = 1;
    stageB(0, 0, 0);

    #pragma unroll 4
    for (int s = 0; s < 128; ++s) {
        const int tt = s & 3;
        float ne2h[4];
        if (tt == 3) {                                   // hoist above stage issue
            const int ct = s >> 2;
            #pragma unroll
            for (int n = 0; n < 4; ++n)
                ne2h[n] = 0.5f * ne2[ct * 128 + wc * 64 + n * 16 + (lane & 15)];
        }
        if (s < 127) {
            const int s1 = s + 1;
            stageB(nxt, s1 >> 2, s1 & 3);
        }
        if (s < 127) asm volatile("s_waitcnt vmcnt(4)" ::: "memory");
        else         asm volatile("s_waitcnt vmcnt(0)" ::: "memory");
        __builtin_amdgcn_s_barrier();
        __builtin_amdgcn_sched_barrier(0);

        #pragma unroll
        for (int kk = 0; kk < 2; ++kk) {
            bf16x8 bg[4];
            #pragma unroll
            for (int n = 0; n < 4; ++n) {
                int cc = wc * 64 + n * 16 + (lane & 15);
                int g = (kk * 4 + (lane >> 4)) ^ (cc & 7);
                bg[n] = *(const bf16x8*)(L + cur * 16384 + cc * 128 + (g << 4));
            }
            #pragma unroll
            for (int m = 0; m < 2; ++m)
                #pragma unroll
                for (int n = 0; n < 4; ++n)
                    acc[m][n] = __builtin_amdgcn_mfma_f32_16x16x32_bf16(
                        af[m][tt * 2 + kk], bg[n], acc[m][n], 0, 0, 0);
        }

        if (tt == 3) {
            const int ct = s >> 2;
            #pragma unroll
            for (int m = 0; m < 2; ++m) {
                #pragma unroll
                for (int j = 0; j < 4; ++j) {
                    float v = fminf(fminf(ne2h[0] - acc[m][0][j], ne2h[1] - acc[m][1][j]),
                                    fminf(ne2h[2] - acc[m][2][j], ne2h[3] - acc[m][3][j]));
                    #pragma unroll
                    for (int off = 1; off < 16; off <<= 1)
                        v = fminf(v, __shfl_xor(v, off, 64));
                    const int rowl = wr * 32 + m * 16 + (lane >> 4) * 4 + j;
                    if ((lane & 15) == 0) atomicMin(&rminp[rowl], enc32(v));
                    float th = fminf(dec32(rminp[rowl]), v) + TAU_H;
                    #pragma unroll
                    for (int n = 0; n < 4; ++n) {
                        float sc = ne2h[n] - acc[m][n][j];
                        if (sc <= th) {
                            int col = ct * 128 + wc * 64 + n * 16 + (lane & 15);
                            int q = (int)rintf(sc * QSC) + 32768;
                            q = max(0, min(65535, q));
                            unsigned pos = atomicAdd(&cntp[rowl], 1u);
                            if (pos < CAP)
                                cand[rowl][pos] = ((unsigned)q << 16) | (unsigned)col;
                        }
                    }
                    acc[m][0][j] = 0.f; acc[m][1][j] = 0.f;
                    acc[m][2][j] = 0.f; acc[m][3][j] = 0.f;
                }
            }
        }
        cur = nxt; nxt = (nxt + 1 == 3) ? 0 : nxt + 1;
    }
    __syncthreads();

    // ---- phase W: q16-prefiltered worklist (r13-validated filter) ----
    unsigned long long* wl = (unsigned long long*)(L + OFF_WL);
    if (tid < 64) {
        unsigned c = cntp[tid];
        if (c <= CAP) {
            float mav = dec32(rminp[tid]);
            int qthr = (int)rintf((mav + TAU_H) * QSC) + 1 + 32768;
            for (unsigned p = 0; p < c; ++p) {
                unsigned e = cand[tid][p];
                if ((int)(e >> 16) <= qthr) {
                    unsigned pos = atomicAdd(wlcnt, 1u);
                    if (pos < WLCAP)
                        wl[pos] = (unsigned long long)((tid << 16) | (e & 0xFFFFu));
                    else cntp[tid] = CAP + 1000u;        // flag overflow
                }
            }
        }
    }
    __syncthreads();

    // ---- phase X: re-stage x f32 [64][260]; init best arrays ----
    float* xl = (float*)(L + OFF_X);
    {
        const float4* g = (const float4*)(x + brow * DIM);
        #pragma unroll
        for (int k = 0; k < 16; ++k) {
            int p = tid + k * 256, gr = p >> 6, gc = p & 63;
            ((float4*)xl)[gr * 65 + gc] = g[p];
        }
    }
    unsigned* bst = (unsigned*)(L + OFF_BST);
    unsigned* bix = (unsigned*)(L + OFF_BIX);
    if (tid < 64) bst[tid] = 0xFFFFFFFFu;
    else if (tid < 128) bix[tid - 64] = 0xFFFFFFFFu;
    __syncthreads();

    // ---- phase S: exact-score worklist (one chain per thread) ----
    const unsigned wn0 = *wlcnt;
    const unsigned wn = wn0 < WLCAP ? wn0 : WLCAP;
    for (unsigned i = tid; i < wn; i += 256) {
        unsigned lo = (unsigned)wl[i];
        int row = lo >> 16, code = lo & 0xFFFFu;
        float sv = exact_score(xl + row * 260, cb + (size_t)code * DIM,
                               nx2l[row], ne2[code]);
        wl[i] = ((unsigned long long)enc32(sv) << 32) | lo;
        atomicMin(&bst[row], enc32(sv));
    }
    for (int r = w; r < 64; r += 4) {                    // overflow rows: full scan
        if (cntp[r] > CAP) {
            float nr = nx2l[r];
            const float* xr = xl + r * 260;
            for (int c = lane; c < NUM_EMB; c += 64) {
                float sv = exact_score(xr, cb + (size_t)c * DIM, nr, ne2[c]);
                atomicMin(&bst[r], enc32(sv));
            }
        }
    }
    __syncthreads();

    // ---- phase R: resolve lowest index among exact ties ----
    for (unsigned i = tid; i < wn; i += 256) {
        unsigned long long v = wl[i];
        unsigned lo = (unsigned)v;
        int row = lo >> 16;
        if ((unsigned)(v >> 32) == bst[row])
            atomicMin(&bix[row], lo & 0xFFFFu);
    }
    for (int r = w; r < 64; r += 4) {
        if (cntp[r] > CAP) {
            float nr = nx2l[r];
            const float* xr = xl + r * 260;
            for (int c = lane; c < NUM_EMB; c += 64) {
                float sv = exact_score(xr, cb + (size_t)c * DIM, nr, ne2[c]);
                if (enc32(sv) == bst[r]) atomicMin(&bix[r], (unsigned)c);
            }
        }
    }
    __syncthreads();

    // ---- phase O: outputs ----
    {
        const int r = tid >> 2, c0 = (tid & 3) * 16;
        int idx = (int)bix[r];
        idx = max(0, min(NUM_EMB - 1, idx));
        const float4* crq = (const float4*)(cb + (size_t)idx * DIM);
        const float4* xr4 = (const float4*)(xl + r * 260);
        float ss = 0.f;
        float4* oq = (float4*)(outp + (brow + r) * DIM);
        #pragma unroll
        for (int k = 0; k < 16; ++k) {
            float4 q = crq[c0 + k], xv = xr4[c0 + k];
            if (writeq) oq[c0 + k] = q;   // blocks 0..63 defer (cbB aliasing)
            float dx = xv.x - q.x, dy = xv.y - q.y, dz = xv.z - q.z, dw = xv.w - q.w;
            ss += dx * dx + dy * dy + dz * dz + dw * dw;
        }
        if ((tid & 3) == 0) {
            outidx[brow + r] = (float)idx;
            atomicAdd(&counts[idx], 1);
        }
        float* red = (float*)(L + OFF_RED);
        red[tid] = ss;
        __syncthreads();
        for (int st2 = 128; st2; st2 >>= 1) {
            if (tid < st2) red[tid] += red[tid + st2];
            __syncthreads();
        }
        if (tid == 0) partials[blockIdx.x] = red[0];
    }
}

// ---- fixup: write quantized rows 0..4095 (deferred due to cbB aliasing) ----
__global__ __launch_bounds__(256) void fixup_q(
        const float* __restrict__ cb, const float* __restrict__ outidx,
        float* __restrict__ outp) {
    const int t = threadIdx.x, b = blockIdx.x;
    const size_t row = (size_t)b * 64 + (t >> 2);
    const int c0 = (t & 3) * 16;
    int idx = (int)outidx[row];
    idx = max(0, min(NUM_EMB - 1, idx));
    const float4* crq = (const float4*)(cb + (size_t)idx * DIM);
    float4* oq = (float4*)(outp + row * DIM);
    #pragma unroll
    for (int k = 0; k < 16; ++k) oq[c0 + k] = crq[c0 + k];
}

__global__ void finalize_kernel(const float* __restrict__ partials, int np,
                                const int* __restrict__ counts,
                                float* __restrict__ out_loss,
                                float* __restrict__ out_perp) {
    __shared__ double sh[256];
    const int t = threadIdx.x;
    double s = 0.0;
    for (int i = t; i < np; i += 256) s += (double)partials[i];
    sh[t] = s; __syncthreads();
    for (int st = 128; st; st >>= 1) { if (t < st) sh[t] += sh[t + st]; __syncthreads(); }
    double sse = sh[0];
    __syncthreads();
    double h = 0.0;
    for (int k = t; k < NUM_EMB; k += 256) {
        double p = (double)counts[k] / (double)N_INPUTS;
        h -= p * log(p + 1e-10);
    }
    sh[t] = h; __syncthreads();
    for (int st = 128; st; st >>= 1) { if (t < st) sh[t] += sh[t + st]; __syncthreads(); }
    if (t == 0) {
        double mse = sse / ((double)N_INPUTS * (double)DIM);
        out_loss[0] = (float)(1.25 * mse);
        out_perp[0] = (float)exp(sh[0]);
    }
}

extern "C" void kernel_launch(void* const* d_in, const int* in_sizes, int n_in,
                              void* d_out, int out_size, void* d_ws, size_t ws_size,
                              hipStream_t stream) {
    const float* x  = (const float*)d_in[0];
    const float* cb = (const float*)d_in[1];
    float* out      = (float*)d_out;

    float* out_q    = out;                              // 16777216 f32
    float* out_loss = out + (size_t)N_INPUTS * DIM;
    float* out_perp = out_loss + 1;
    float* out_idx  = out_perp + 1;                     // 65536 f32

    // ws: ne2 16K | counts 16K | partials 4K  (well under proven 300 KB)
    float* ne2      = (float*)d_ws;
    int*   counts   = (int*)((char*)d_ws + 16384);
    float* partials = (float*)((char*)d_ws + 32768);

    hipMemsetAsync(counts, 0, NUM_EMB * sizeof(int), stream);

    // codebook: norms + bf16 into out-row tails (rows 0..4095, bytes +384..896)
    prep_cb<<<NUM_EMB / 64, 256, 0, stream>>>(cb, ne2, (char*)out);

    gemm_fused<<<N_INPUTS / 64, 256, 0, stream>>>(
        x, (const char*)out + 384, cb, ne2, out, out_idx, counts, partials);

    fixup_q<<<NUM_EMB / 64, 256, 0, stream>>>(cb, out_idx, out);

    finalize_kernel<<<1, 256, 0, stream>>>(partials, N_INPUTS / 64, counts,
                                           out_loss, out_perp);
}